// Round 7
// baseline (308.721 us; speedup 1.0000x reference)
//
#include <hip/hip_runtime.h>
#include <hip/hip_cooperative_groups.h>

namespace cg = cooperative_groups;

#define DEV static __device__ __forceinline__

typedef unsigned short u16;
typedef __bf16 bf16_t;
typedef __bf16 bf16x8 __attribute__((ext_vector_type(8)));
typedef float f32x4 __attribute__((ext_vector_type(4)));
typedef u16 u16x8 __attribute__((ext_vector_type(8)));

static constexpr int Bb = 8;     // batch
static constexpr int Nn = 4096;  // tokens per batch
static constexpr int Dd = 256;   // d
static constexpr int DP = 512;   // d_prime

// ---------------- async global->LDS (16B, wave-uniform LDS base + lane*16) ----------------
DEV void gload16(const void* g, void* l) {
  __builtin_amdgcn_global_load_lds(
      (__attribute__((address_space(1))) void*)(unsigned long long)(g),
      (__attribute__((address_space(3))) void*)(unsigned)(unsigned long long)(l),
      16, 0, 0);
}

DEV u16 f2bf(float x) { bf16_t h = (bf16_t)x; return __builtin_bit_cast(u16, h); }
DEV float bf2f(u16 v) { unsigned u = ((unsigned)v) << 16; return __builtin_bit_cast(float, u); }
DEV float gelu_exact(float x) { return 0.5f * x * (1.0f + erff(x * 0.70710678118654752f)); }

// ------------- 128x128 tile mainloop, 2-phase double-buffered (T3-minimum) ----------------
// A: M-rows x K ; B: N-rows x K (B^T layout). 4 waves, each 64x64, 16x16x32 bf16 MFMA.
// ldsA/ldsB must each hold 2*128*32 u16 (16 KB).
DEV void gemm_tile(const u16* Ag, int lda, const u16* Bg, int ldb,
                   int k0, int ksteps, u16* ldsA, u16* ldsB, f32x4 acc[4][4]) {
  const int tid  = threadIdx.x;
  const int wave = tid >> 6, lane = tid & 63;
  const int wr = wave >> 1, wc = wave & 1;
  const int lr = lane & 15, lk = (lane >> 4) * 8;
  const int srow = lane >> 2;          // 0..15 row within 16-row chunk
  const int skb  = (lane & 3) * 8;     // k element offset of this lane's 16B
  const int c0 = wave * 2, c1 = c0 + 1;
  const size_t ga0 = (size_t)(c0 * 16 + srow) * lda + skb;
  const size_t ga1 = (size_t)(c1 * 16 + srow) * lda + skb;
  const size_t gb0 = (size_t)(c0 * 16 + srow) * ldb + skb;
  const size_t gb1 = (size_t)(c1 * 16 + srow) * ldb + skb;
  u16* la0 = ldsA + c0 * 512; u16* la1 = ldsA + c1 * 512;
  u16* lb0 = ldsB + c0 * 512; u16* lb1 = ldsB + c1 * 512;

  // prologue: stage K-step 0 into buffer 0
  gload16(Ag + ga0 + k0, la0); gload16(Ag + ga1 + k0, la1);
  gload16(Bg + gb0 + k0, lb0); gload16(Bg + gb1 + k0, lb1);
  asm volatile("s_waitcnt vmcnt(0)" ::: "memory");
  __syncthreads();

  int cur = 0;
  for (int kt = 0; kt < ksteps; ++kt) {
    const int nbuf = cur ^ 1;
    if (kt + 1 < ksteps) {               // issue next-step loads BEFORE compute (overlap)
      const int kk = k0 + (kt + 1) * 32;
      gload16(Ag + ga0 + kk, la0 + nbuf * 4096);
      gload16(Ag + ga1 + kk, la1 + nbuf * 4096);
      gload16(Bg + gb0 + kk, lb0 + nbuf * 4096);
      gload16(Bg + gb1 + kk, lb1 + nbuf * 4096);
    }
    const u16* pa = ldsA + cur * 4096;
    const u16* pb = ldsB + cur * 4096;
    bf16x8 af[4], bfr[4];
#pragma unroll
    for (int m = 0; m < 4; ++m)
      af[m] = *(const bf16x8*)(pa + (wr * 64 + m * 16 + lr) * 32 + lk);
#pragma unroll
    for (int n = 0; n < 4; ++n)
      bfr[n] = *(const bf16x8*)(pb + (wc * 64 + n * 16 + lr) * 32 + lk);
#pragma unroll
    for (int m = 0; m < 4; ++m)
#pragma unroll
      for (int n = 0; n < 4; ++n)
        acc[m][n] = __builtin_amdgcn_mfma_f32_16x16x32_bf16(af[m], bfr[n], acc[m][n], 0, 0, 0);
    asm volatile("s_waitcnt vmcnt(0)" ::: "memory");   // next buffer's loads done
    __syncthreads();                                    // all waves done reading cur
    cur = nbuf;
  }
}

DEV void acc_zero(f32x4 acc[4][4]) {
#pragma unroll
  for (int m = 0; m < 4; ++m)
#pragma unroll
    for (int n = 0; n < 4; ++n) {
      f32x4 z = {0.f, 0.f, 0.f, 0.f};
      acc[m][n] = z;
    }
}

// ============ S1 mega-kernel: Xp/XpT/s_part (blocks 0..2047) + Wh prep (2048..2143) ========
__global__ __launch_bounds__(256) void k_s1(const float* __restrict__ X, const float* __restrict__ P,
                                            const float* __restrict__ Wh1, const float* __restrict__ Wh2,
                                            u16* __restrict__ Xp, u16* __restrict__ XpT,
                                            float* __restrict__ s_part,
                                            u16* __restrict__ WhT1, u16* __restrict__ Wbf2) {
  __shared__ u16 lt[64 * 65];
  const int bid = blockIdx.x;
  const int t = threadIdx.x;
  if (bid < 2048) {
    // ---- Xp = bf16(X+P) [b,n,d], XpT [b,d,n], s_part[b][nt][d] = per-tile column sums ----
    const int b  = bid >> 8;
    const int nt = (bid >> 2) & 63;
    const int dt = bid & 3;
    const int n0 = nt * 64, d0 = dt * 64;
    const int r = t >> 2, c0 = (t & 3) * 16;
    const size_t gbase = ((size_t)(b * Nn + n0 + r)) * Dd + d0 + c0;
    u16x8 lo, hi;
#pragma unroll
    for (int i = 0; i < 4; ++i) {
      float4 xv = *(const float4*)(X + gbase + i * 4);
      float4 pv = *(const float4*)(P + gbase + i * 4);
      u16 a0 = f2bf(xv.x + pv.x), a1 = f2bf(xv.y + pv.y);
      u16 a2 = f2bf(xv.z + pv.z), a3 = f2bf(xv.w + pv.w);
      if (i < 2) { lo[i*4+0]=a0; lo[i*4+1]=a1; lo[i*4+2]=a2; lo[i*4+3]=a3; }
      else       { int q=(i-2)*4; hi[q+0]=a0; hi[q+1]=a1; hi[q+2]=a2; hi[q+3]=a3; }
      lt[r * 65 + c0 + i*4 + 0] = a0; lt[r * 65 + c0 + i*4 + 1] = a1;
      lt[r * 65 + c0 + i*4 + 2] = a2; lt[r * 65 + c0 + i*4 + 3] = a3;
    }
    *(u16x8*)(Xp + gbase)     = lo;
    *(u16x8*)(Xp + gbase + 8) = hi;
    __syncthreads();
    const int dd = t >> 2, nc0 = (t & 3) * 16;
    u16x8 olo, ohi;
    float colsum = 0.f;
#pragma unroll
    for (int i = 0; i < 8; ++i) { olo[i] = lt[(nc0 + i) * 65 + dd]; colsum += bf2f(olo[i]); }
#pragma unroll
    for (int i = 0; i < 8; ++i) { ohi[i] = lt[(nc0 + 8 + i) * 65 + dd]; colsum += bf2f(ohi[i]); }
    const size_t obase = ((size_t)(b * Dd + d0 + dd)) * Nn + n0 + nc0;
    *(u16x8*)(XpT + obase)     = olo;
    *(u16x8*)(XpT + obase + 8) = ohi;
    colsum += __shfl_xor(colsum, 1);
    colsum += __shfl_xor(colsum, 2);
    if ((t & 3) == 0) s_part[(size_t)(b * 64 + nt) * Dd + d0 + dd] = colsum;
  } else if (bid < 2048 + 32) {
    // ---- transpose Wh1 [256][512] -> WhT1 [512][256] (bf16) ----
    const int wb = bid - 2048;
    const int rt = (wb >> 3) & 3;       // d tile
    const int ct = wb & 7;              // p tile
    const int r0 = rt * 64, c0t = ct * 64;
    const int r = t >> 2, c0 = (t & 3) * 16;
    const size_t gbase = (size_t)(r0 + r) * DP + c0t + c0;
#pragma unroll
    for (int i = 0; i < 4; ++i) {
      float4 v = *(const float4*)(Wh1 + gbase + i * 4);
      lt[r * 65 + c0 + i*4 + 0] = f2bf(v.x); lt[r * 65 + c0 + i*4 + 1] = f2bf(v.y);
      lt[r * 65 + c0 + i*4 + 2] = f2bf(v.z); lt[r * 65 + c0 + i*4 + 3] = f2bf(v.w);
    }
    __syncthreads();
    const int pp = t >> 2, dc0 = (t & 3) * 16;
    u16x8 olo, ohi;
#pragma unroll
    for (int i = 0; i < 8; ++i) olo[i] = lt[(dc0 + i) * 65 + pp];
#pragma unroll
    for (int i = 0; i < 8; ++i) ohi[i] = lt[(dc0 + 8 + i) * 65 + pp];
    u16* out = WhT1 + (size_t)(c0t + pp) * Dd + r0 + dc0;
    *(u16x8*)(out)     = olo;
    *(u16x8*)(out + 8) = ohi;
  } else {
    // ---- straight cast Wh2 -> Wbf2 (bf16) ----
    const int idx = ((bid - 2048 - 32) * 256 + t) * 8;
    float4 v0 = *(const float4*)(Wh2 + idx);
    float4 v1 = *(const float4*)(Wh2 + idx + 4);
    u16x8 o;
    o[0]=f2bf(v0.x); o[1]=f2bf(v0.y); o[2]=f2bf(v0.z); o[3]=f2bf(v0.w);
    o[4]=f2bf(v1.x); o[5]=f2bf(v1.y); o[6]=f2bf(v1.z); o[7]=f2bf(v1.w);
    *(u16x8*)(Wbf2 + idx) = o;
  }
}

// ============ cooperative mega-kernel: gram -> gsum -> pmAT -> h -> y (512 blocks) =========
// LDS: single 34,816 B buffer. gemm_tile uses [0:16K)A + [16K:32K)B; ctb (34.8K) ALIASES it —
// safe because ctb is only touched after gemm_tile's final __syncthreads.
__global__ __launch_bounds__(256) void k_mega(
    const u16* __restrict__ XpT, float* __restrict__ G_part,
    const float* __restrict__ s_part, u16* __restrict__ Gb,
    float* __restrict__ s, float* __restrict__ c,
    const u16* __restrict__ WhT1, const float* __restrict__ bh1,
    const float* __restrict__ bh2, u16* __restrict__ AT,
    const u16* __restrict__ Wbf2, u16* __restrict__ HT,
    const u16* __restrict__ Xp, float* __restrict__ Y) {
  __shared__ __align__(16) u16 smem[17408];      // 34,816 B total
  u16* smemA = smem;                              // 8192 u16 = 2 x 128x32
  u16* smemB = smem + 8192;                       // 8192 u16
  u16* ctb   = smem;                              // 17408 u16, aliases A+B (post-gemm only)
  cg::grid_group grid = cg::this_grid();
  const int bid0 = blockIdx.x;
  const int tid = threadIdx.x;
  const int wave = tid >> 6, lane = tid & 63;
  const int wr = wave >> 1, wc = wave & 1, lr = lane & 15, lq = lane >> 4;

  // ---- phase 1: gram (blocks 0..255, XCD-swizzled) ∥ s-reduce + c-zero (blocks 256..263) --
  if (bid0 < 256) {
    const int bid = (bid0 & 7) * 32 + (bid0 >> 3);   // bijective: 256 = 8 XCD * 32
    const int kc = bid & 7;
    const int tn = (bid >> 3) & 1;
    const int tm = (bid >> 4) & 1;
    const int b  = bid >> 5;
    const u16* Ag = XpT + (size_t)(b * Dd + tm * 128) * Nn;
    const u16* Bg = XpT + (size_t)(b * Dd + tn * 128) * Nn;
    f32x4 acc[4][4];
    acc_zero(acc);
    gemm_tile(Ag, Nn, Bg, Nn, kc * 512, 16, smemA, smemB, acc);
    float* base = G_part + (size_t)kc * (Bb * Dd * Dd) + (size_t)(b * Dd + tm * 128) * Dd + tn * 128;
#pragma unroll
    for (int m = 0; m < 4; ++m)
#pragma unroll
      for (int n = 0; n < 4; ++n)
#pragma unroll
        for (int j = 0; j < 4; ++j)
          base[(size_t)(wr * 64 + m * 16 + lq * 4 + j) * Dd + wc * 64 + n * 16 + lr] = acc[m][n][j];
  } else if (bid0 < 264) {
    const int b = bid0 - 256, d = tid;
    float sum = 0.f;
#pragma unroll 8
    for (int nt = 0; nt < 64; ++nt) sum += s_part[(size_t)(b * 64 + nt) * Dd + d];
    s[b * Dd + d] = sum;
    c[b * Dd + d] = 0.f;
  }
  grid.sync();

  // ---- phase 2: Gb = bf16(sum of 8 slabs) (blocks 0..255) ----
  if (bid0 < 256) {
    const int e = (bid0 * 256 + tid) * 8;
    float4 a0 = {0.f,0.f,0.f,0.f}, a1 = {0.f,0.f,0.f,0.f};
#pragma unroll
    for (int k = 0; k < 8; ++k) {
      const float* sp = G_part + (size_t)k * (Bb * Dd * Dd) + e;
      float4 v0 = *(const float4*)(sp);
      float4 v1 = *(const float4*)(sp + 4);
      a0.x += v0.x; a0.y += v0.y; a0.z += v0.z; a0.w += v0.w;
      a1.x += v1.x; a1.y += v1.y; a1.z += v1.z; a1.w += v1.w;
    }
    u16x8 o;
    o[0]=f2bf(a0.x); o[1]=f2bf(a0.y); o[2]=f2bf(a0.z); o[3]=f2bf(a0.w);
    o[4]=f2bf(a1.x); o[5]=f2bf(a1.y); o[6]=f2bf(a1.z); o[7]=f2bf(a1.w);
    *(u16x8*)(Gb + e) = o;
  }
  grid.sync();

  // ---- phase 3: AT = bf16(gelu(Wh1^T G + bh1 ⊗ s)) + c partial (blocks 0..63) ----
  if (bid0 < 64) {
    const int tn = bid0 & 1;
    const int tm = (bid0 >> 1) & 3;
    const int b  = bid0 >> 3;
    const int p0 = tm * 128, d0 = tn * 128;
    const u16* Ag = WhT1 + (size_t)p0 * Dd;                    // rows p, K=d
    const u16* Bg = Gb + (size_t)(b * Dd + d0) * Dd;           // rows d_out, K=d (G symmetric)
    f32x4 acc[4][4];
    acc_zero(acc);
    gemm_tile(Ag, Dd, Bg, Dd, 0, Dd / 32, smemA, smemB, acc);
#pragma unroll
    for (int n = 0; n < 4; ++n) {
      const int col = wc * 64 + n * 16 + lr;              // d within tile
      const float sv = s[b * Dd + d0 + col];
#pragma unroll
      for (int m = 0; m < 4; ++m) {
#pragma unroll
        for (int j = 0; j < 4; ++j) {
          const int row = wr * 64 + m * 16 + lq * 4 + j;  // p within tile
          const float pm = acc[m][n][j] + bh1[p0 + row] * sv;
          ctb[col * 136 + row] = f2bf(gelu_exact(pm));
        }
      }
    }
    __syncthreads();
#pragma unroll
    for (int it = 0; it < 8; ++it) {
      const int id = tid + it * 256;
      const int dl = id >> 4, ch = id & 15;
      *(u16x8*)(AT + (size_t)(b * Dd + d0 + dl) * DP + p0 + ch * 8) =
          *(const u16x8*)(ctb + dl * 136 + ch * 8);
    }
    const int ccol = tid >> 1;      // 0..127 d-index within tile
    const int chalf = tid & 1;      // which 64-p half
    float csum = 0.f;
#pragma unroll
    for (int q = 0; q < 8; ++q) {
      u16x8 av = *(const u16x8*)(ctb + ccol * 136 + chalf * 64 + q * 8);
#pragma unroll
      for (int i = 0; i < 8; ++i) csum += bh2[p0 + chalf * 64 + q * 8 + i] * bf2f(av[i]);
    }
    csum += __shfl_xor(csum, 1);
    if (chalf == 0) atomicAdd(c + b * Dd + d0 + ccol, csum);
  }
  grid.sync();

  // ---- phase 4: HT = bf16(Wh2 @ A)^T (blocks 0..31) ----
  if (bid0 < 32) {
    const int tn = bid0 & 1;
    const int tm = (bid0 >> 1) & 1;
    const int b  = bid0 >> 2;
    const int k0 = tm * 128, d0 = tn * 128;
    const u16* Ag = Wbf2 + (size_t)k0 * DP;                    // rows kd, K=p
    const u16* Bg = AT + (size_t)(b * Dd + d0) * DP;           // rows d_out, K=p
    f32x4 acc[4][4];
    acc_zero(acc);
    gemm_tile(Ag, DP, Bg, DP, 0, DP / 32, smemA, smemB, acc);
#pragma unroll
    for (int n = 0; n < 4; ++n) {
      const int col = wc * 64 + n * 16 + lr;              // d_out within tile
#pragma unroll
      for (int m = 0; m < 4; ++m)
#pragma unroll
        for (int j = 0; j < 4; ++j)
          ctb[col * 136 + wr * 64 + m * 16 + lq * 4 + j] = f2bf(acc[m][n][j]);
    }
    __syncthreads();
#pragma unroll
    for (int it = 0; it < 8; ++it) {
      const int id = tid + it * 256;
      const int dl = id >> 4, ch = id & 15;
      *(u16x8*)(HT + (size_t)(b * Dd + d0 + dl) * Dd + k0 + ch * 8) =
          *(const u16x8*)(ctb + dl * 136 + ch * 8);
    }
  }
  grid.sync();

  // ---- phase 5: Y = Xp @ H + c (all 512 blocks, XCD-swizzled) ----
  {
    const int bid = (bid0 & 7) * 64 + (bid0 >> 3);
    const int tn = bid & 1;
    const int tm = (bid >> 1) & 31;
    const int b  = bid >> 6;
    const u16* Ag = Xp + (size_t)(b * Nn + tm * 128) * Dd;
    const u16* Bg = HT + (size_t)(b * Dd + tn * 128) * Dd;
    f32x4 acc[4][4];
    acc_zero(acc);
    gemm_tile(Ag, Dd, Bg, Dd, 0, Dd / 32, smemA, smemB, acc);
    float* base = Y + (size_t)(b * Nn + tm * 128) * Dd + tn * 128;
#pragma unroll
    for (int n = 0; n < 4; ++n) {
      const int col = wc * 64 + n * 16 + lr;
      const float cv = c[b * Dd + tn * 128 + col];
#pragma unroll
      for (int m = 0; m < 4; ++m)
#pragma unroll
        for (int j = 0; j < 4; ++j)
          base[(size_t)(wr * 64 + m * 16 + lq * 4 + j) * Dd + col] = acc[m][n][j] + cv;
    }
  }
}

// ================= fallback kernels (round-5 proven path) =================
__global__ __launch_bounds__(256) void k_gram(const u16* __restrict__ XpT, float* __restrict__ G_part) {
  __shared__ __align__(16) u16 ldsA[2 * 128 * 32];
  __shared__ __align__(16) u16 ldsB[2 * 128 * 32];
  const int bid0 = blockIdx.x;
  const int bid = (bid0 & 7) * 32 + (bid0 >> 3);
  const int kc = bid & 7;
  const int tn = (bid >> 3) & 1;
  const int tm = (bid >> 4) & 1;
  const int b  = bid >> 5;
  const u16* Ag = XpT + (size_t)(b * Dd + tm * 128) * Nn;
  const u16* Bg = XpT + (size_t)(b * Dd + tn * 128) * Nn;
  f32x4 acc[4][4];
  acc_zero(acc);
  gemm_tile(Ag, Nn, Bg, Nn, kc * 512, 16, ldsA, ldsB, acc);
  const int tid = threadIdx.x, wave = tid >> 6, lane = tid & 63;
  const int wr = wave >> 1, wc = wave & 1, lr = lane & 15, lq = lane >> 4;
  float* base = G_part + (size_t)kc * (Bb * Dd * Dd) + (size_t)(b * Dd + tm * 128) * Dd + tn * 128;
#pragma unroll
  for (int m = 0; m < 4; ++m)
#pragma unroll
    for (int n = 0; n < 4; ++n)
#pragma unroll
      for (int j = 0; j < 4; ++j)
        base[(size_t)(wr * 64 + m * 16 + lq * 4 + j) * Dd + wc * 64 + n * 16 + lr] = acc[m][n][j];
}

__global__ __launch_bounds__(256) void k_gsum(const float* __restrict__ G_part,
                                              const float* __restrict__ s_part,
                                              u16* __restrict__ Gb, float* __restrict__ s,
                                              float* __restrict__ c) {
  const int bid = blockIdx.x;
  const int t = threadIdx.x;
  if (bid < 8) {
    const int b = bid, d = t;
    float sum = 0.f;
#pragma unroll 8
    for (int nt = 0; nt < 64; ++nt) sum += s_part[(size_t)(b * 64 + nt) * Dd + d];
    s[b * Dd + d] = sum;
    c[b * Dd + d] = 0.f;
  } else {
    const int e = ((bid - 8) * 256 + t) * 8;
    float4 a0 = {0.f,0.f,0.f,0.f}, a1 = {0.f,0.f,0.f,0.f};
#pragma unroll
    for (int k = 0; k < 8; ++k) {
      const float* sp = G_part + (size_t)k * (Bb * Dd * Dd) + e;
      float4 v0 = *(const float4*)(sp);
      float4 v1 = *(const float4*)(sp + 4);
      a0.x += v0.x; a0.y += v0.y; a0.z += v0.z; a0.w += v0.w;
      a1.x += v1.x; a1.y += v1.y; a1.z += v1.z; a1.w += v1.w;
    }
    u16x8 o;
    o[0]=f2bf(a0.x); o[1]=f2bf(a0.y); o[2]=f2bf(a0.z); o[3]=f2bf(a0.w);
    o[4]=f2bf(a1.x); o[5]=f2bf(a1.y); o[6]=f2bf(a1.z); o[7]=f2bf(a1.w);
    *(u16x8*)(Gb + e) = o;
  }
}

__global__ __launch_bounds__(256) void k_pmAT(const u16* __restrict__ WhT1, const u16* __restrict__ Gb,
                                              const float* __restrict__ bh1, const float* __restrict__ s,
                                              const float* __restrict__ bh2,
                                              u16* __restrict__ AT, float* __restrict__ c) {
  __shared__ __align__(16) u16 ldsA[2 * 128 * 32];
  __shared__ __align__(16) u16 ldsB[2 * 128 * 32];
  __shared__ __align__(16) u16 ct[128 * 136];
  const int bid = blockIdx.x;
  const int tn = bid & 1;
  const int tm = (bid >> 1) & 3;
  const int b  = bid >> 3;
  const int p0 = tm * 128, d0 = tn * 128;
  const u16* Ag = WhT1 + (size_t)p0 * Dd;
  const u16* Bg = Gb + (size_t)(b * Dd + d0) * Dd;
  f32x4 acc[4][4];
  acc_zero(acc);
  gemm_tile(Ag, Dd, Bg, Dd, 0, Dd / 32, ldsA, ldsB, acc);
  const int tid = threadIdx.x, wave = tid >> 6, lane = tid & 63;
  const int wr = wave >> 1, wc = wave & 1, lr = lane & 15, lq = lane >> 4;
#pragma unroll
  for (int n = 0; n < 4; ++n) {
    const int col = wc * 64 + n * 16 + lr;
    const float sv = s[b * Dd + d0 + col];
#pragma unroll
    for (int m = 0; m < 4; ++m) {
#pragma unroll
      for (int j = 0; j < 4; ++j) {
        const int row = wr * 64 + m * 16 + lq * 4 + j;
        const float pm = acc[m][n][j] + bh1[p0 + row] * sv;
        ct[col * 136 + row] = f2bf(gelu_exact(pm));
      }
    }
  }
  __syncthreads();
#pragma unroll
  for (int it = 0; it < 8; ++it) {
    const int id = tid + it * 256;
    const int dl = id >> 4, ch = id & 15;
    *(u16x8*)(AT + (size_t)(b * Dd + d0 + dl) * DP + p0 + ch * 8) =
        *(const u16x8*)(ct + dl * 136 + ch * 8);
  }
  const int ccol = tid >> 1;
  const int chalf = tid & 1;
  float csum = 0.f;
#pragma unroll
  for (int q = 0; q < 8; ++q) {
    u16x8 av = *(const u16x8*)(ct + ccol * 136 + chalf * 64 + q * 8);
#pragma unroll
    for (int i = 0; i < 8; ++i) csum += bh2[p0 + chalf * 64 + q * 8 + i] * bf2f(av[i]);
  }
  csum += __shfl_xor(csum, 1);
  if (chalf == 0) atomicAdd(c + b * Dd + d0 + ccol, csum);
}

__global__ __launch_bounds__(256) void k_h(const u16* __restrict__ Wbf2, const u16* __restrict__ AT,
                                           u16* __restrict__ HT) {
  __shared__ __align__(16) u16 ldsA[2 * 128 * 32];
  __shared__ __align__(16) u16 ldsB[2 * 128 * 32];
  __shared__ __align__(16) u16 ct[128 * 136];
  const int bid = blockIdx.x;
  const int tn = bid & 1;
  const int tm = (bid >> 1) & 1;
  const int b  = bid >> 2;
  const int k0 = tm * 128, d0 = tn * 128;
  const u16* Ag = Wbf2 + (size_t)k0 * DP;
  const u16* Bg = AT + (size_t)(b * Dd + d0) * DP;
  f32x4 acc[4][4];
  acc_zero(acc);
  gemm_tile(Ag, DP, Bg, DP, 0, DP / 32, ldsA, ldsB, acc);
  const int tid = threadIdx.x, wave = tid >> 6, lane = tid & 63;
  const int wr = wave >> 1, wc = wave & 1, lr = lane & 15, lq = lane >> 4;
#pragma unroll
  for (int n = 0; n < 4; ++n) {
    const int col = wc * 64 + n * 16 + lr;
#pragma unroll
    for (int m = 0; m < 4; ++m)
#pragma unroll
      for (int j = 0; j < 4; ++j)
        ct[col * 136 + wr * 64 + m * 16 + lq * 4 + j] = f2bf(acc[m][n][j]);
  }
  __syncthreads();
#pragma unroll
  for (int it = 0; it < 8; ++it) {
    const int id = tid + it * 256;
    const int dl = id >> 4, ch = id & 15;
    *(u16x8*)(HT + (size_t)(b * Dd + d0 + dl) * Dd + k0 + ch * 8) =
        *(const u16x8*)(ct + dl * 136 + ch * 8);
  }
}

__global__ __launch_bounds__(256) void k_y(const u16* __restrict__ Xp, const u16* __restrict__ HT,
                                           const float* __restrict__ c, float* __restrict__ Y) {
  __shared__ __align__(16) u16 ldsA[2 * 128 * 32];
  __shared__ __align__(16) u16 ldsB[2 * 128 * 32];
  const int bid0 = blockIdx.x;
  const int bid = (bid0 & 7) * 64 + (bid0 >> 3);
  const int tn = bid & 1;
  const int tm = (bid >> 1) & 31;
  const int b  = bid >> 6;
  const u16* Ag = Xp + (size_t)(b * Nn + tm * 128) * Dd;
  const u16* Bg = HT + (size_t)(b * Dd + tn * 128) * Dd;
  f32x4 acc[4][4];
  acc_zero(acc);
  gemm_tile(Ag, Dd, Bg, Dd, 0, Dd / 32, ldsA, ldsB, acc);
  const int tid = threadIdx.x, wave = tid >> 6, lane = tid & 63;
  const int wr = wave >> 1, wc = wave & 1, lr = lane & 15, lq = lane >> 4;
  float* base = Y + (size_t)(b * Nn + tm * 128) * Dd + tn * 128;
#pragma unroll
  for (int n = 0; n < 4; ++n) {
    const int col = wc * 64 + n * 16 + lr;
    const float cv = c[b * Dd + tn * 128 + col];
#pragma unroll
    for (int m = 0; m < 4; ++m)
#pragma unroll
      for (int j = 0; j < 4; ++j)
        base[(size_t)(wr * 64 + m * 16 + lq * 4 + j) * Dd + col] = acc[m][n][j] + cv;
  }
}

// ---------------- launcher ----------------
extern "C" void kernel_launch(void* const* d_in, const int* in_sizes, int n_in,
                              void* d_out, int out_size, void* d_ws, size_t ws_size,
                              hipStream_t stream) {
  const float* X   = (const float*)d_in[0];
  const float* P   = (const float*)d_in[1];
  const float* Wh1 = (const float*)d_in[2];
  const float* bh1 = (const float*)d_in[3];
  const float* Wh2 = (const float*)d_in[4];
  const float* bh2 = (const float*)d_in[5];
  float* Y = (float*)d_out;
  char* ws = (char*)d_ws;

  // workspace layout (bytes)
  u16*   Xp     = (u16*)(ws);                     // 16,777,216
  u16*   XpT    = (u16*)(ws + 16777216);          // 16,777,216
  u16*   WhT1   = (u16*)(ws + 33554432);          //    262,144
  u16*   Wbf2   = (u16*)(ws + 33816576);          //    262,144
  float* G_part = (float*)(ws + 34078720);        // 16,777,216  (8 split-K slabs)
  float* s_part = (float*)(ws + 50855936);        //    524,288
  float* s      = (float*)(ws + 51380224);        //      8,192
  float* c      = (float*)(ws + 51388416);        //      8,192
  u16*   Gb     = (u16*)(ws + 51396608);          //  1,048,576
  u16*   AT     = (u16*)(ws + 52445184);          //  2,097,152
  u16*   HT     = (u16*)(ws + 54542336);          //  1,048,576
  const size_t WS_NEED = 55590912;
  if (ws_size < WS_NEED) return;

  k_s1<<<2144, 256, 0, stream>>>(X, P, Wh1, Wh2, Xp, XpT, s_part, WhT1, Wbf2);

  void* args[] = {(void*)&XpT, (void*)&G_part, (void*)&s_part, (void*)&Gb, (void*)&s,
                  (void*)&c, (void*)&WhT1, (void*)&bh1, (void*)&bh2, (void*)&AT,
                  (void*)&Wbf2, (void*)&HT, (void*)&Xp, (void*)&Y};
  hipError_t err = hipLaunchCooperativeKernel((const void*)k_mega, dim3(512), dim3(256),
                                              args, 0, stream);
  if (err != hipSuccess) {
    // fallback: proven round-5 multi-kernel path (identical math)
    k_gram<<<256,  256, 0, stream>>>(XpT, G_part);
    k_gsum<<<264,  256, 0, stream>>>(G_part, s_part, Gb, s, c);
    k_pmAT<<<64,   256, 0, stream>>>(WhT1, Gb, bh1, s, bh2, AT, c);
    k_h   <<<32,   256, 0, stream>>>(Wbf2, AT, HT);
    k_y   <<<512,  256, 0, stream>>>(Xp, HT, c, Y);
  }
}

// Round 8
// 91.994 us; speedup vs baseline: 3.3559x; 3.3559x over previous
//
#include <hip/hip_runtime.h>

#define DEV static __device__ __forceinline__

typedef unsigned short u16;
typedef __bf16 bf16_t;
typedef __bf16 bf16x8 __attribute__((ext_vector_type(8)));
typedef float f32x4 __attribute__((ext_vector_type(4)));
typedef u16 u16x8 __attribute__((ext_vector_type(8)));

static constexpr int Bb = 8;     // batch
static constexpr int Nn = 4096;  // tokens per batch
static constexpr int Dd = 256;   // d
static constexpr int DP = 512;   // d_prime

// ---------------- async global->LDS (16B, wave-uniform LDS base + lane*16) ----------------
DEV void gload16(const void* g, void* l) {
  __builtin_amdgcn_global_load_lds(
      (__attribute__((address_space(1))) void*)(unsigned long long)(g),
      (__attribute__((address_space(3))) void*)(unsigned)(unsigned long long)(l),
      16, 0, 0);
}

DEV u16 f2bf(float x) { bf16_t h = (bf16_t)x; return __builtin_bit_cast(u16, h); }
DEV float bf2f(u16 v) { unsigned u = ((unsigned)v) << 16; return __builtin_bit_cast(float, u); }
DEV float gelu_exact(float x) { return 0.5f * x * (1.0f + erff(x * 0.70710678118654752f)); }

// ------------- 128x128 tile mainloop, 2-phase double-buffered (bf16 A and B) --------------
// A: M-rows x K ; B: N-rows x K (B^T layout). 4 waves, each 64x64, 16x16x32 bf16 MFMA.
// ldsA/ldsB each hold 2*128*32 u16 (16 KB).
DEV void gemm_tile(const u16* Ag, int lda, const u16* Bg, int ldb,
                   int k0, int ksteps, u16* ldsA, u16* ldsB, f32x4 acc[4][4]) {
  const int tid  = threadIdx.x;
  const int wave = tid >> 6, lane = tid & 63;
  const int wr = wave >> 1, wc = wave & 1;
  const int lr = lane & 15, lk = (lane >> 4) * 8;
  const int srow = lane >> 2;          // 0..15 row within 16-row chunk
  const int skb  = (lane & 3) * 8;     // k element offset of this lane's 16B
  const int c0 = wave * 2, c1 = c0 + 1;
  const size_t ga0 = (size_t)(c0 * 16 + srow) * lda + skb;
  const size_t ga1 = (size_t)(c1 * 16 + srow) * lda + skb;
  const size_t gb0 = (size_t)(c0 * 16 + srow) * ldb + skb;
  const size_t gb1 = (size_t)(c1 * 16 + srow) * ldb + skb;
  u16* la0 = ldsA + c0 * 512; u16* la1 = ldsA + c1 * 512;
  u16* lb0 = ldsB + c0 * 512; u16* lb1 = ldsB + c1 * 512;

  gload16(Ag + ga0 + k0, la0); gload16(Ag + ga1 + k0, la1);
  gload16(Bg + gb0 + k0, lb0); gload16(Bg + gb1 + k0, lb1);
  asm volatile("s_waitcnt vmcnt(0)" ::: "memory");
  __syncthreads();

  int cur = 0;
  for (int kt = 0; kt < ksteps; ++kt) {
    const int nbuf = cur ^ 1;
    if (kt + 1 < ksteps) {
      const int kk = k0 + (kt + 1) * 32;
      gload16(Ag + ga0 + kk, la0 + nbuf * 4096);
      gload16(Ag + ga1 + kk, la1 + nbuf * 4096);
      gload16(Bg + gb0 + kk, lb0 + nbuf * 4096);
      gload16(Bg + gb1 + kk, lb1 + nbuf * 4096);
    }
    const u16* pa = ldsA + cur * 4096;
    const u16* pb = ldsB + cur * 4096;
    bf16x8 af[4], bfr[4];
#pragma unroll
    for (int m = 0; m < 4; ++m)
      af[m] = *(const bf16x8*)(pa + (wr * 64 + m * 16 + lr) * 32 + lk);
#pragma unroll
    for (int n = 0; n < 4; ++n)
      bfr[n] = *(const bf16x8*)(pb + (wc * 64 + n * 16 + lr) * 32 + lk);
#pragma unroll
    for (int m = 0; m < 4; ++m)
#pragma unroll
      for (int n = 0; n < 4; ++n)
        acc[m][n] = __builtin_amdgcn_mfma_f32_16x16x32_bf16(af[m], bfr[n], acc[m][n], 0, 0, 0);
    asm volatile("s_waitcnt vmcnt(0)" ::: "memory");
    __syncthreads();
    cur = nbuf;
  }
}

DEV void acc_zero(f32x4 acc[4][4]) {
#pragma unroll
  for (int m = 0; m < 4; ++m)
#pragma unroll
    for (int n = 0; n < 4; ++n) {
      f32x4 z = {0.f, 0.f, 0.f, 0.f};
      acc[m][n] = z;
    }
}

// ===== S1: Xp/XpT/s_part (0..2047) + Wh1^T (2048..2079) + Wh2 cast (2080..2143) + G zero ===
__global__ __launch_bounds__(256) void k_s1(const float* __restrict__ X, const float* __restrict__ P,
                                            const float* __restrict__ Wh1, const float* __restrict__ Wh2,
                                            u16* __restrict__ Xp, u16* __restrict__ XpT,
                                            float* __restrict__ s_part,
                                            u16* __restrict__ WhT1, u16* __restrict__ Wbf2,
                                            float* __restrict__ G) {
  __shared__ u16 lt[64 * 65];
  const int bid = blockIdx.x;
  const int t = threadIdx.x;
  if (bid < 2048) {
    const int b  = bid >> 8;
    const int nt = (bid >> 2) & 63;
    const int dt = bid & 3;
    const int n0 = nt * 64, d0 = dt * 64;
    const int r = t >> 2, c0 = (t & 3) * 16;
    const size_t gbase = ((size_t)(b * Nn + n0 + r)) * Dd + d0 + c0;
    u16x8 lo, hi;
#pragma unroll
    for (int i = 0; i < 4; ++i) {
      float4 xv = *(const float4*)(X + gbase + i * 4);
      float4 pv = *(const float4*)(P + gbase + i * 4);
      u16 a0 = f2bf(xv.x + pv.x), a1 = f2bf(xv.y + pv.y);
      u16 a2 = f2bf(xv.z + pv.z), a3 = f2bf(xv.w + pv.w);
      if (i < 2) { lo[i*4+0]=a0; lo[i*4+1]=a1; lo[i*4+2]=a2; lo[i*4+3]=a3; }
      else       { int q=(i-2)*4; hi[q+0]=a0; hi[q+1]=a1; hi[q+2]=a2; hi[q+3]=a3; }
      lt[r * 65 + c0 + i*4 + 0] = a0; lt[r * 65 + c0 + i*4 + 1] = a1;
      lt[r * 65 + c0 + i*4 + 2] = a2; lt[r * 65 + c0 + i*4 + 3] = a3;
    }
    *(u16x8*)(Xp + gbase)     = lo;
    *(u16x8*)(Xp + gbase + 8) = hi;
    __syncthreads();
    const int dd = t >> 2, nc0 = (t & 3) * 16;
    u16x8 olo, ohi;
    float colsum = 0.f;
#pragma unroll
    for (int i = 0; i < 8; ++i) { olo[i] = lt[(nc0 + i) * 65 + dd]; colsum += bf2f(olo[i]); }
#pragma unroll
    for (int i = 0; i < 8; ++i) { ohi[i] = lt[(nc0 + 8 + i) * 65 + dd]; colsum += bf2f(ohi[i]); }
    const size_t obase = ((size_t)(b * Dd + d0 + dd)) * Nn + n0 + nc0;
    *(u16x8*)(XpT + obase)     = olo;
    *(u16x8*)(XpT + obase + 8) = ohi;
    colsum += __shfl_xor(colsum, 1);
    colsum += __shfl_xor(colsum, 2);
    if ((t & 3) == 0) s_part[(size_t)(b * 64 + nt) * Dd + d0 + dd] = colsum;
  } else if (bid < 2048 + 32) {
    const int wb = bid - 2048;
    const int rt = (wb >> 3) & 3;
    const int ct = wb & 7;
    const int r0 = rt * 64, c0t = ct * 64;
    const int r = t >> 2, c0 = (t & 3) * 16;
    const size_t gbase = (size_t)(r0 + r) * DP + c0t + c0;
#pragma unroll
    for (int i = 0; i < 4; ++i) {
      float4 v = *(const float4*)(Wh1 + gbase + i * 4);
      lt[r * 65 + c0 + i*4 + 0] = f2bf(v.x); lt[r * 65 + c0 + i*4 + 1] = f2bf(v.y);
      lt[r * 65 + c0 + i*4 + 2] = f2bf(v.z); lt[r * 65 + c0 + i*4 + 3] = f2bf(v.w);
    }
    __syncthreads();
    const int pp = t >> 2, dc0 = (t & 3) * 16;
    u16x8 olo, ohi;
#pragma unroll
    for (int i = 0; i < 8; ++i) olo[i] = lt[(dc0 + i) * 65 + pp];
#pragma unroll
    for (int i = 0; i < 8; ++i) ohi[i] = lt[(dc0 + 8 + i) * 65 + pp];
    u16* out = WhT1 + (size_t)(c0t + pp) * Dd + r0 + dc0;
    *(u16x8*)(out)     = olo;
    *(u16x8*)(out + 8) = ohi;
  } else if (bid < 2048 + 32 + 64) {
    const int idx = ((bid - 2048 - 32) * 256 + t) * 8;
    float4 v0 = *(const float4*)(Wh2 + idx);
    float4 v1 = *(const float4*)(Wh2 + idx + 4);
    u16x8 o;
    o[0]=f2bf(v0.x); o[1]=f2bf(v0.y); o[2]=f2bf(v0.z); o[3]=f2bf(v0.w);
    o[4]=f2bf(v1.x); o[5]=f2bf(v1.y); o[6]=f2bf(v1.z); o[7]=f2bf(v1.w);
    *(u16x8*)(Wbf2 + idx) = o;
  } else {
    // ---- zero G (2 MB f32): 256 blocks x 256 threads x 8 floats ----
    const int idx = ((bid - 2144) * 256 + t) * 8;
    float4 z = {0.f, 0.f, 0.f, 0.f};
    *(float4*)(G + idx)     = z;
    *(float4*)(G + idx + 4) = z;
  }
}

// ======== k_gram: G[b] += XpT[b] @ XpT[b]^T (split-K=8, f32 atomicAdd into zeroed G) =======
// blocks 0..255 gram (XCD-swizzled); blocks 256..263 zero c.
__global__ __launch_bounds__(256) void k_gram(const u16* __restrict__ XpT, float* __restrict__ G,
                                              float* __restrict__ c) {
  __shared__ __align__(16) u16 ldsA[2 * 128 * 32];
  __shared__ __align__(16) u16 ldsB[2 * 128 * 32];
  const int bid0 = blockIdx.x;
  const int tid = threadIdx.x;
  if (bid0 >= 256) {
    c[(bid0 - 256) * Dd + tid] = 0.f;
    return;
  }
  const int bid = (bid0 & 7) * 32 + (bid0 >> 3);   // bijective: 256 = 8 XCD * 32
  const int kc = bid & 7;
  const int tn = (bid >> 3) & 1;
  const int tm = (bid >> 4) & 1;
  const int b  = bid >> 5;
  const u16* Ag = XpT + (size_t)(b * Dd + tm * 128) * Nn;
  const u16* Bg = XpT + (size_t)(b * Dd + tn * 128) * Nn;
  f32x4 acc[4][4];
  acc_zero(acc);
  gemm_tile(Ag, Nn, Bg, Nn, kc * 512, 16, ldsA, ldsB, acc);
  const int wave = tid >> 6, lane = tid & 63;
  const int wr = wave >> 1, wc = wave & 1, lr = lane & 15, lq = lane >> 4;
  float* base = G + (size_t)(b * Dd + tm * 128) * Dd + tn * 128;
#pragma unroll
  for (int m = 0; m < 4; ++m)
#pragma unroll
    for (int n = 0; n < 4; ++n)
#pragma unroll
      for (int j = 0; j < 4; ++j)
        atomicAdd(base + (size_t)(wr * 64 + m * 16 + lq * 4 + j) * Dd + wc * 64 + n * 16 + lr,
                  acc[m][n][j]);
}

// ==== k_pmAT: AT[b][d][p] = bf16(gelu(Wh1^T G + bh1 ⊗ s)); c[b][d] += bh2·A partial ======
// B operand is G in f32 (cast to bf16 at fragment build). Single-buffered staging.
// s computed in-block from s_part. LDS: 8K(A) + 16K(Bf) + 34.8K(ct) + 0.5K(sv) = 59.9 KB.
__global__ __launch_bounds__(256) void k_pmAT(const u16* __restrict__ WhT1, const float* __restrict__ G,
                                              const float* __restrict__ s_part,
                                              const float* __restrict__ bh1, const float* __restrict__ bh2,
                                              u16* __restrict__ AT, float* __restrict__ c) {
  __shared__ __align__(16) u16 ldsA[128 * 32];
  __shared__ __align__(16) float ldsBf[128 * 32];
  __shared__ __align__(16) u16 ct[128 * 136];
  __shared__ float sv[128];
  const int bid = blockIdx.x;        // 8b * 4tm(p) * 2tn(d)
  const int tn = bid & 1;
  const int tm = (bid >> 1) & 3;
  const int b  = bid >> 3;
  const int p0 = tm * 128, d0 = tn * 128;
  const int tid = threadIdx.x;
  const int wave = tid >> 6, lane = tid & 63;
  const int wr = wave >> 1, wc = wave & 1, lr = lane & 15, lq = lane >> 4;
  const int lk = lq * 8;

  // prologue: s[d0+j] = sum_nt s_part[b][nt][d0+j]   (threads 0..127)
  if (tid < 128) {
    float sum = 0.f;
#pragma unroll 8
    for (int nt = 0; nt < 64; ++nt) sum += s_part[(size_t)(b * 64 + nt) * Dd + d0 + tid];
    sv[tid] = sum;
  }

  const u16*   Ag = WhT1 + (size_t)p0 * Dd;                 // rows p, K=d (bf16)
  const float* Bg = G + (size_t)(b * Dd + d0) * Dd;         // rows d_out, K=d (f32, G symmetric)

  const int srowA = lane >> 2, skbA = (lane & 3) * 8;       // A: 16B = 8 bf16
  const int srowB = lane >> 3, skbB = (lane & 7) * 4;       // B: 16B = 4 f32
  const int c0 = wave * 2, c1 = c0 + 1;

  f32x4 acc[4][4];
  acc_zero(acc);
  for (int kt = 0; kt < 8; ++kt) {
    const int kk = kt * 32;
    // stage A (2 chunks/wave, 1 load each) and B f32 (2 chunks/wave, 2 loads each)
    gload16(Ag + (size_t)(c0 * 16 + srowA) * Dd + kk + skbA, ldsA + c0 * 512);
    gload16(Ag + (size_t)(c1 * 16 + srowA) * Dd + kk + skbA, ldsA + c1 * 512);
    gload16(Bg + (size_t)(c0 * 16 + srowB) * Dd + kk + skbB, ldsBf + c0 * 512);
    gload16(Bg + (size_t)(c0 * 16 + 8 + srowB) * Dd + kk + skbB, ldsBf + c0 * 512 + 256);
    gload16(Bg + (size_t)(c1 * 16 + srowB) * Dd + kk + skbB, ldsBf + c1 * 512);
    gload16(Bg + (size_t)(c1 * 16 + 8 + srowB) * Dd + kk + skbB, ldsBf + c1 * 512 + 256);
    asm volatile("s_waitcnt vmcnt(0)" ::: "memory");
    __syncthreads();
    bf16x8 af[4], bfr[4];
#pragma unroll
    for (int m = 0; m < 4; ++m)
      af[m] = *(const bf16x8*)(ldsA + (wr * 64 + m * 16 + lr) * 32 + lk);
#pragma unroll
    for (int n = 0; n < 4; ++n) {
      const float* bp = ldsBf + (wc * 64 + n * 16 + lr) * 32 + lk;
      float4 v0 = *(const float4*)(bp);
      float4 v1 = *(const float4*)(bp + 4);
      bf16x8 f;
      f[0]=(bf16_t)v0.x; f[1]=(bf16_t)v0.y; f[2]=(bf16_t)v0.z; f[3]=(bf16_t)v0.w;
      f[4]=(bf16_t)v1.x; f[5]=(bf16_t)v1.y; f[6]=(bf16_t)v1.z; f[7]=(bf16_t)v1.w;
      bfr[n] = f;
    }
#pragma unroll
    for (int m = 0; m < 4; ++m)
#pragma unroll
      for (int n = 0; n < 4; ++n)
        acc[m][n] = __builtin_amdgcn_mfma_f32_16x16x32_bf16(af[m], bfr[n], acc[m][n], 0, 0, 0);
    __syncthreads();
  }

#pragma unroll
  for (int n = 0; n < 4; ++n) {
    const int col = wc * 64 + n * 16 + lr;              // d within tile
    const float svv = sv[col];
#pragma unroll
    for (int m = 0; m < 4; ++m) {
#pragma unroll
      for (int j = 0; j < 4; ++j) {
        const int row = wr * 64 + m * 16 + lq * 4 + j;  // p within tile
        const float pm = acc[m][n][j] + bh1[p0 + row] * svv;
        ct[col * 136 + row] = f2bf(gelu_exact(pm));
      }
    }
  }
  __syncthreads();
#pragma unroll
  for (int it = 0; it < 8; ++it) {
    const int id = tid + it * 256;
    const int dl = id >> 4, ch = id & 15;
    *(u16x8*)(AT + (size_t)(b * Dd + d0 + dl) * DP + p0 + ch * 8) =
        *(const u16x8*)(ct + dl * 136 + ch * 8);
  }
  const int ccol = tid >> 1;
  const int chalf = tid & 1;
  float csum = 0.f;
#pragma unroll
  for (int q = 0; q < 8; ++q) {
    u16x8 av = *(const u16x8*)(ct + ccol * 136 + chalf * 64 + q * 8);
#pragma unroll
    for (int i = 0; i < 8; ++i) csum += bh2[p0 + chalf * 64 + q * 8 + i] * bf2f(av[i]);
  }
  csum += __shfl_xor(csum, 1);
  if (chalf == 0) atomicAdd(c + b * Dd + d0 + ccol, csum);
}

// ---------------- kernel: HT[b][d_out][kd] = bf16(Wh2 @ A)^T ----------------
__global__ __launch_bounds__(256) void k_h(const u16* __restrict__ Wbf2, const u16* __restrict__ AT,
                                           u16* __restrict__ HT) {
  __shared__ __align__(16) u16 ldsA[2 * 128 * 32];
  __shared__ __align__(16) u16 ldsB[2 * 128 * 32];
  __shared__ __align__(16) u16 ct[128 * 136];
  const int bid = blockIdx.x;
  const int tn = bid & 1;
  const int tm = (bid >> 1) & 1;
  const int b  = bid >> 2;
  const int k0 = tm * 128, d0 = tn * 128;
  const u16* Ag = Wbf2 + (size_t)k0 * DP;
  const u16* Bg = AT + (size_t)(b * Dd + d0) * DP;
  f32x4 acc[4][4];
  acc_zero(acc);
  gemm_tile(Ag, DP, Bg, DP, 0, DP / 32, ldsA, ldsB, acc);
  const int tid = threadIdx.x, wave = tid >> 6, lane = tid & 63;
  const int wr = wave >> 1, wc = wave & 1, lr = lane & 15, lq = lane >> 4;
#pragma unroll
  for (int n = 0; n < 4; ++n) {
    const int col = wc * 64 + n * 16 + lr;
#pragma unroll
    for (int m = 0; m < 4; ++m)
#pragma unroll
      for (int j = 0; j < 4; ++j)
        ct[col * 136 + wr * 64 + m * 16 + lq * 4 + j] = f2bf(acc[m][n][j]);
  }
  __syncthreads();
#pragma unroll
  for (int it = 0; it < 8; ++it) {
    const int id = tid + it * 256;
    const int dl = id >> 4, ch = id & 15;
    *(u16x8*)(HT + (size_t)(b * Dd + d0 + dl) * Dd + k0 + ch * 8) =
        *(const u16x8*)(ct + dl * 136 + ch * 8);
  }
}

// ---------------- kernel: Y[b][n][d] = Xp[b] @ H[b] + c[b][d] (XCD-swizzled) --------------
__global__ __launch_bounds__(256) void k_y(const u16* __restrict__ Xp, const u16* __restrict__ HT,
                                           const float* __restrict__ c, float* __restrict__ Y) {
  __shared__ __align__(16) u16 ldsA[2 * 128 * 32];
  __shared__ __align__(16) u16 ldsB[2 * 128 * 32];
  const int bid0 = blockIdx.x;
  const int bid = (bid0 & 7) * 64 + (bid0 >> 3);
  const int tn = bid & 1;
  const int tm = (bid >> 1) & 31;
  const int b  = bid >> 6;
  const u16* Ag = Xp + (size_t)(b * Nn + tm * 128) * Dd;
  const u16* Bg = HT + (size_t)(b * Dd + tn * 128) * Dd;
  f32x4 acc[4][4];
  acc_zero(acc);
  gemm_tile(Ag, Dd, Bg, Dd, 0, Dd / 32, ldsA, ldsB, acc);
  const int tid = threadIdx.x, wave = tid >> 6, lane = tid & 63;
  const int wr = wave >> 1, wc = wave & 1, lr = lane & 15, lq = lane >> 4;
  float* base = Y + (size_t)(b * Nn + tm * 128) * Dd + tn * 128;
#pragma unroll
  for (int n = 0; n < 4; ++n) {
    const int col = wc * 64 + n * 16 + lr;
    const float cv = c[b * Dd + tn * 128 + col];
#pragma unroll
    for (int m = 0; m < 4; ++m)
#pragma unroll
      for (int j = 0; j < 4; ++j)
        base[(size_t)(wr * 64 + m * 16 + lq * 4 + j) * Dd + col] = acc[m][n][j] + cv;
  }
}

// ---------------- launcher ----------------
extern "C" void kernel_launch(void* const* d_in, const int* in_sizes, int n_in,
                              void* d_out, int out_size, void* d_ws, size_t ws_size,
                              hipStream_t stream) {
  const float* X   = (const float*)d_in[0];
  const float* P   = (const float*)d_in[1];
  const float* Wh1 = (const float*)d_in[2];
  const float* bh1 = (const float*)d_in[3];
  const float* Wh2 = (const float*)d_in[4];
  const float* bh2 = (const float*)d_in[5];
  float* Y = (float*)d_out;
  char* ws = (char*)d_ws;

  // workspace layout (bytes)
  u16*   Xp     = (u16*)(ws);                     // 16,777,216
  u16*   XpT    = (u16*)(ws + 16777216);          // 16,777,216
  u16*   WhT1   = (u16*)(ws + 33554432);          //    262,144
  u16*   Wbf2   = (u16*)(ws + 33816576);          //    262,144
  float* G      = (float*)(ws + 34078720);        //  2,097,152
  float* s_part = (float*)(ws + 36175872);        //    524,288
  float* c      = (float*)(ws + 36700160);        //      8,192
  u16*   AT     = (u16*)(ws + 36708352);          //  2,097,152
  u16*   HT     = (u16*)(ws + 38805504);          //  1,048,576
  const size_t WS_NEED = 39854080;
  if (ws_size < WS_NEED) return;

  k_s1  <<<2400, 256, 0, stream>>>(X, P, Wh1, Wh2, Xp, XpT, s_part, WhT1, Wbf2, G);
  k_gram<<<264,  256, 0, stream>>>(XpT, G, c);
  k_pmAT<<<64,   256, 0, stream>>>(WhT1, G, s_part, bh1, bh2, AT, c);
  k_h   <<<32,   256, 0, stream>>>(Wbf2, AT, HT);
  k_y   <<<512,  256, 0, stream>>>(Xp, HT, c, Y);
}

// Round 9
// 72.135 us; speedup vs baseline: 4.2797x; 1.2753x over previous
//
#include <hip/hip_runtime.h>

#define DEV static __device__ __forceinline__

typedef unsigned short u16;
typedef __bf16 bf16_t;
typedef __bf16 bf16x8 __attribute__((ext_vector_type(8)));
typedef float f32x4 __attribute__((ext_vector_type(4)));
typedef u16 u16x8 __attribute__((ext_vector_type(8)));

static constexpr int Bb = 8;     // batch
static constexpr int Nn = 4096;  // tokens per batch
static constexpr int Dd = 256;   // d
static constexpr int DP = 512;   // d_prime

// ---------------- async global->LDS (16B, wave-uniform LDS base + lane*16) ----------------
DEV void gload16(const void* g, void* l) {
  __builtin_amdgcn_global_load_lds(
      (__attribute__((address_space(1))) void*)(unsigned long long)(g),
      (__attribute__((address_space(3))) void*)(unsigned)(unsigned long long)(l),
      16, 0, 0);
}

DEV u16 f2bf(float x) { bf16_t h = (bf16_t)x; return __builtin_bit_cast(u16, h); }
DEV float bf2f(u16 v) { unsigned u = ((unsigned)v) << 16; return __builtin_bit_cast(float, u); }
DEV float gelu_exact(float x) { return 0.5f * x * (1.0f + erff(x * 0.70710678118654752f)); }

// ------- 128 x (NT*32) tile mainloop, 2-phase double-buffered; 4 waves, 16x16x32 MFMA -----
// A: 128 rows x K ; B: NT*32 rows x K (B^T layout). Wave tile = 64 x (NT*16).
// ldsA: 2*128*32 u16 (16 KB). ldsB: 2*NT*32*32 u16 (NT=4: 16 KB, NT=2: 8 KB).
template <int NT>
DEV void gemm_tile(const u16* Ag, int lda, const u16* Bg, int ldb,
                   int k0, int ksteps, u16* ldsA, u16* ldsB, f32x4 acc[4][NT]) {
  const int tid  = threadIdx.x;
  const int wave = tid >> 6, lane = tid & 63;
  const int wr = wave >> 1, wc = wave & 1;
  const int lr = lane & 15, lk = (lane >> 4) * 8;
  const int srow = lane >> 2;          // 0..15 row within 16-row chunk
  const int skb  = (lane & 3) * 8;     // k element offset of this lane's 16B
  constexpr int BCH = NT / 2;          // B chunks (16 rows) per wave
  constexpr int BBUF = NT * 1024;      // B buffer stride in u16

  const int ca0 = wave * 2, ca1 = ca0 + 1;
  const size_t ga0 = (size_t)(ca0 * 16 + srow) * lda + skb;
  const size_t ga1 = (size_t)(ca1 * 16 + srow) * lda + skb;
  u16* la0 = ldsA + ca0 * 512; u16* la1 = ldsA + ca1 * 512;
  size_t gb[BCH]; u16* lb[BCH];
#pragma unroll
  for (int i = 0; i < BCH; ++i) {
    const int ch = wave * BCH + i;
    gb[i] = (size_t)(ch * 16 + srow) * ldb + skb;
    lb[i] = ldsB + ch * 512;
  }

  // prologue: stage K-step 0 into buffer 0
  gload16(Ag + ga0 + k0, la0); gload16(Ag + ga1 + k0, la1);
#pragma unroll
  for (int i = 0; i < BCH; ++i) gload16(Bg + gb[i] + k0, lb[i]);
  asm volatile("s_waitcnt vmcnt(0)" ::: "memory");
  __syncthreads();

  int cur = 0;
  for (int kt = 0; kt < ksteps; ++kt) {
    const int nbuf = cur ^ 1;
    if (kt + 1 < ksteps) {               // issue next-step loads BEFORE compute (overlap)
      const int kk = k0 + (kt + 1) * 32;
      gload16(Ag + ga0 + kk, la0 + nbuf * 4096);
      gload16(Ag + ga1 + kk, la1 + nbuf * 4096);
#pragma unroll
      for (int i = 0; i < BCH; ++i) gload16(Bg + gb[i] + kk, lb[i] + nbuf * BBUF);
    }
    const u16* pa = ldsA + cur * 4096;
    const u16* pb = ldsB + cur * BBUF;
    bf16x8 af[4], bfr[NT];
#pragma unroll
    for (int m = 0; m < 4; ++m)
      af[m] = *(const bf16x8*)(pa + (wr * 64 + m * 16 + lr) * 32 + lk);
#pragma unroll
    for (int n = 0; n < NT; ++n)
      bfr[n] = *(const bf16x8*)(pb + (wc * (NT * 16) + n * 16 + lr) * 32 + lk);
#pragma unroll
    for (int m = 0; m < 4; ++m)
#pragma unroll
      for (int n = 0; n < NT; ++n)
        acc[m][n] = __builtin_amdgcn_mfma_f32_16x16x32_bf16(af[m], bfr[n], acc[m][n], 0, 0, 0);
    asm volatile("s_waitcnt vmcnt(0)" ::: "memory");   // next buffer's loads done
    __syncthreads();                                    // all waves done reading cur
    cur = nbuf;
  }
}

template <int NT>
DEV void acc_zero(f32x4 acc[4][NT]) {
#pragma unroll
  for (int m = 0; m < 4; ++m)
#pragma unroll
    for (int n = 0; n < NT; ++n) {
      f32x4 z = {0.f, 0.f, 0.f, 0.f};
      acc[m][n] = z;
    }
}

// ============ S1 mega-kernel: Xp/XpT/s_part (blocks 0..2047) + Wh prep (2048..2143) ========
__global__ __launch_bounds__(256) void k_s1(const float* __restrict__ X, const float* __restrict__ P,
                                            const float* __restrict__ Wh1, const float* __restrict__ Wh2,
                                            u16* __restrict__ Xp, u16* __restrict__ XpT,
                                            float* __restrict__ s_part,
                                            u16* __restrict__ WhT1, u16* __restrict__ Wbf2) {
  __shared__ u16 lt[64 * 65];
  const int bid = blockIdx.x;
  const int t = threadIdx.x;
  if (bid < 2048) {
    const int b  = bid >> 8;
    const int nt = (bid >> 2) & 63;
    const int dt = bid & 3;
    const int n0 = nt * 64, d0 = dt * 64;
    const int r = t >> 2, c0 = (t & 3) * 16;
    const size_t gbase = ((size_t)(b * Nn + n0 + r)) * Dd + d0 + c0;
    u16x8 lo, hi;
#pragma unroll
    for (int i = 0; i < 4; ++i) {
      float4 xv = *(const float4*)(X + gbase + i * 4);
      float4 pv = *(const float4*)(P + gbase + i * 4);
      u16 a0 = f2bf(xv.x + pv.x), a1 = f2bf(xv.y + pv.y);
      u16 a2 = f2bf(xv.z + pv.z), a3 = f2bf(xv.w + pv.w);
      if (i < 2) { lo[i*4+0]=a0; lo[i*4+1]=a1; lo[i*4+2]=a2; lo[i*4+3]=a3; }
      else       { int q=(i-2)*4; hi[q+0]=a0; hi[q+1]=a1; hi[q+2]=a2; hi[q+3]=a3; }
      lt[r * 65 + c0 + i*4 + 0] = a0; lt[r * 65 + c0 + i*4 + 1] = a1;
      lt[r * 65 + c0 + i*4 + 2] = a2; lt[r * 65 + c0 + i*4 + 3] = a3;
    }
    *(u16x8*)(Xp + gbase)     = lo;
    *(u16x8*)(Xp + gbase + 8) = hi;
    __syncthreads();
    const int dd = t >> 2, nc0 = (t & 3) * 16;
    u16x8 olo, ohi;
    float colsum = 0.f;
#pragma unroll
    for (int i = 0; i < 8; ++i) { olo[i] = lt[(nc0 + i) * 65 + dd]; colsum += bf2f(olo[i]); }
#pragma unroll
    for (int i = 0; i < 8; ++i) { ohi[i] = lt[(nc0 + 8 + i) * 65 + dd]; colsum += bf2f(ohi[i]); }
    const size_t obase = ((size_t)(b * Dd + d0 + dd)) * Nn + n0 + nc0;
    *(u16x8*)(XpT + obase)     = olo;
    *(u16x8*)(XpT + obase + 8) = ohi;
    colsum += __shfl_xor(colsum, 1);
    colsum += __shfl_xor(colsum, 2);
    if ((t & 3) == 0) s_part[(size_t)(b * 64 + nt) * Dd + d0 + dd] = colsum;
  } else if (bid < 2048 + 32) {
    const int wb = bid - 2048;
    const int rt = (wb >> 3) & 3;
    const int ct = wb & 7;
    const int r0 = rt * 64, c0t = ct * 64;
    const int r = t >> 2, c0 = (t & 3) * 16;
    const size_t gbase = (size_t)(r0 + r) * DP + c0t + c0;
#pragma unroll
    for (int i = 0; i < 4; ++i) {
      float4 v = *(const float4*)(Wh1 + gbase + i * 4);
      lt[r * 65 + c0 + i*4 + 0] = f2bf(v.x); lt[r * 65 + c0 + i*4 + 1] = f2bf(v.y);
      lt[r * 65 + c0 + i*4 + 2] = f2bf(v.z); lt[r * 65 + c0 + i*4 + 3] = f2bf(v.w);
    }
    __syncthreads();
    const int pp = t >> 2, dc0 = (t & 3) * 16;
    u16x8 olo, ohi;
#pragma unroll
    for (int i = 0; i < 8; ++i) olo[i] = lt[(dc0 + i) * 65 + pp];
#pragma unroll
    for (int i = 0; i < 8; ++i) ohi[i] = lt[(dc0 + 8 + i) * 65 + pp];
    u16* out = WhT1 + (size_t)(c0t + pp) * Dd + r0 + dc0;
    *(u16x8*)(out)     = olo;
    *(u16x8*)(out + 8) = ohi;
  } else {
    const int idx = ((bid - 2048 - 32) * 256 + t) * 8;
    float4 v0 = *(const float4*)(Wh2 + idx);
    float4 v1 = *(const float4*)(Wh2 + idx + 4);
    u16x8 o;
    o[0]=f2bf(v0.x); o[1]=f2bf(v0.y); o[2]=f2bf(v0.z); o[3]=f2bf(v0.w);
    o[4]=f2bf(v1.x); o[5]=f2bf(v1.y); o[6]=f2bf(v1.z); o[7]=f2bf(v1.w);
    *(u16x8*)(Wbf2 + idx) = o;
  }
}

// ====== k_gram: G_part[kc][b][256][256] (bf16) = XpT[b] @ XpT[b]^T K-slice, plain stores ===
// 512 blocks of 128x64 tiles (NT=2): 8b * 2tm * 4tn * 8kc. XCD-swizzled: batch b -> XCD b.
__global__ __launch_bounds__(256) void k_gram(const u16* __restrict__ XpT, u16* __restrict__ G_part) {
  __shared__ __align__(16) u16 ldsA[2 * 128 * 32];
  __shared__ __align__(16) u16 ldsB[2 * 64 * 32];
  const int bid0 = blockIdx.x;
  const int bid = (bid0 & 7) * 64 + (bid0 >> 3);   // bijective: 512 = 8 XCD * 64
  const int kc = bid & 7;
  const int tn = (bid >> 3) & 3;
  const int tm = (bid >> 5) & 1;
  const int b  = bid >> 6;
  const u16* Ag = XpT + (size_t)(b * Dd + tm * 128) * Nn;
  const u16* Bg = XpT + (size_t)(b * Dd + tn * 64) * Nn;
  f32x4 acc[4][2];
  acc_zero<2>(acc);
  gemm_tile<2>(Ag, Nn, Bg, Nn, kc * 512, 16, ldsA, ldsB, acc);
  const int tid = threadIdx.x, wave = tid >> 6, lane = tid & 63;
  const int wr = wave >> 1, wc = wave & 1, lr = lane & 15, lq = lane >> 4;
  u16* base = G_part + (size_t)kc * (Bb * Dd * Dd) + (size_t)(b * Dd + tm * 128) * Dd + tn * 64;
#pragma unroll
  for (int m = 0; m < 4; ++m)
#pragma unroll
    for (int n = 0; n < 2; ++n)
#pragma unroll
      for (int j = 0; j < 4; ++j)
        base[(size_t)(wr * 64 + m * 16 + lq * 4 + j) * Dd + wc * 32 + n * 16 + lr] =
            f2bf(acc[m][n][j]);
}

// ==== k_gsum: blocks 0..7 -> s reduce + zero c ; blocks 8..263 -> Gb = bf16(sum slabs) ====
__global__ __launch_bounds__(256) void k_gsum(const u16* __restrict__ G_part,
                                              const float* __restrict__ s_part,
                                              u16* __restrict__ Gb, float* __restrict__ s,
                                              float* __restrict__ c) {
  const int bid = blockIdx.x;
  const int t = threadIdx.x;
  if (bid < 8) {
    const int b = bid, d = t;
    float sum = 0.f;
#pragma unroll 8
    for (int nt = 0; nt < 64; ++nt) sum += s_part[(size_t)(b * 64 + nt) * Dd + d];
    s[b * Dd + d] = sum;
    c[b * Dd + d] = 0.f;
  } else {
    const int e = ((bid - 8) * 256 + t) * 8;
    float a[8] = {0.f,0.f,0.f,0.f,0.f,0.f,0.f,0.f};
#pragma unroll
    for (int k = 0; k < 8; ++k) {
      u16x8 v = *(const u16x8*)(G_part + (size_t)k * (Bb * Dd * Dd) + e);
#pragma unroll
      for (int i = 0; i < 8; ++i) a[i] += bf2f(v[i]);
    }
    u16x8 o;
#pragma unroll
    for (int i = 0; i < 8; ++i) o[i] = f2bf(a[i]);
    *(u16x8*)(Gb + e) = o;
  }
}

// ==== k_pmAT: AT[b][d][p] = bf16(gelu(Wh1^T G + bh1 ⊗ s)); c[b][d] += bh2·A partial ======
__global__ __launch_bounds__(256) void k_pmAT(const u16* __restrict__ WhT1, const u16* __restrict__ Gb,
                                              const float* __restrict__ bh1, const float* __restrict__ s,
                                              const float* __restrict__ bh2,
                                              u16* __restrict__ AT, float* __restrict__ c) {
  __shared__ __align__(16) u16 ldsA[2 * 128 * 32];
  __shared__ __align__(16) u16 ldsB[2 * 128 * 32];
  __shared__ __align__(16) u16 ct[128 * 136];
  const int bid = blockIdx.x;        // 8b * 4tm(p) * 2tn(d)
  const int tn = bid & 1;
  const int tm = (bid >> 1) & 3;
  const int b  = bid >> 3;
  const int p0 = tm * 128, d0 = tn * 128;
  const u16* Ag = WhT1 + (size_t)p0 * Dd;
  const u16* Bg = Gb + (size_t)(b * Dd + d0) * Dd;
  f32x4 acc[4][4];
  acc_zero<4>(acc);
  gemm_tile<4>(Ag, Dd, Bg, Dd, 0, Dd / 32, ldsA, ldsB, acc);
  const int tid = threadIdx.x, wave = tid >> 6, lane = tid & 63;
  const int wr = wave >> 1, wc = wave & 1, lr = lane & 15, lq = lane >> 4;
#pragma unroll
  for (int n = 0; n < 4; ++n) {
    const int col = wc * 64 + n * 16 + lr;
    const float sv = s[b * Dd + d0 + col];
#pragma unroll
    for (int m = 0; m < 4; ++m) {
#pragma unroll
      for (int j = 0; j < 4; ++j) {
        const int row = wr * 64 + m * 16 + lq * 4 + j;
        const float pm = acc[m][n][j] + bh1[p0 + row] * sv;
        ct[col * 136 + row] = f2bf(gelu_exact(pm));
      }
    }
  }
  __syncthreads();
#pragma unroll
  for (int it = 0; it < 8; ++it) {
    const int id = tid + it * 256;
    const int dl = id >> 4, ch = id & 15;
    *(u16x8*)(AT + (size_t)(b * Dd + d0 + dl) * DP + p0 + ch * 8) =
        *(const u16x8*)(ct + dl * 136 + ch * 8);
  }
  const int ccol = tid >> 1;
  const int chalf = tid & 1;
  float csum = 0.f;
#pragma unroll
  for (int q = 0; q < 8; ++q) {
    u16x8 av = *(const u16x8*)(ct + ccol * 136 + chalf * 64 + q * 8);
#pragma unroll
    for (int i = 0; i < 8; ++i) csum += bh2[p0 + chalf * 64 + q * 8 + i] * bf2f(av[i]);
  }
  csum += __shfl_xor(csum, 1);
  if (chalf == 0) atomicAdd(c + b * Dd + d0 + ccol, csum);
}

// ---------------- kernel: HT[b][d_out][kd] = bf16(Wh2 @ A)^T ----------------
__global__ __launch_bounds__(256) void k_h(const u16* __restrict__ Wbf2, const u16* __restrict__ AT,
                                           u16* __restrict__ HT) {
  __shared__ __align__(16) u16 ldsA[2 * 128 * 32];
  __shared__ __align__(16) u16 ldsB[2 * 128 * 32];
  __shared__ __align__(16) u16 ct[128 * 136];
  const int bid = blockIdx.x;
  const int tn = bid & 1;
  const int tm = (bid >> 1) & 1;
  const int b  = bid >> 2;
  const int k0 = tm * 128, d0 = tn * 128;
  const u16* Ag = Wbf2 + (size_t)k0 * DP;
  const u16* Bg = AT + (size_t)(b * Dd + d0) * DP;
  f32x4 acc[4][4];
  acc_zero<4>(acc);
  gemm_tile<4>(Ag, DP, Bg, DP, 0, DP / 32, ldsA, ldsB, acc);
  const int tid = threadIdx.x, wave = tid >> 6, lane = tid & 63;
  const int wr = wave >> 1, wc = wave & 1, lr = lane & 15, lq = lane >> 4;
#pragma unroll
  for (int n = 0; n < 4; ++n) {
    const int col = wc * 64 + n * 16 + lr;
#pragma unroll
    for (int m = 0; m < 4; ++m)
#pragma unroll
      for (int j = 0; j < 4; ++j)
        ct[col * 136 + wr * 64 + m * 16 + lq * 4 + j] = f2bf(acc[m][n][j]);
  }
  __syncthreads();
#pragma unroll
  for (int it = 0; it < 8; ++it) {
    const int id = tid + it * 256;
    const int dl = id >> 4, ch = id & 15;
    *(u16x8*)(HT + (size_t)(b * Dd + d0 + dl) * Dd + k0 + ch * 8) =
        *(const u16x8*)(ct + dl * 136 + ch * 8);
  }
}

// -------- kernel: Y[b][n][d] = Xp[b] @ H[b] + c[b][d]  (1024 blocks of 128x64, NT=2) ------
__global__ __launch_bounds__(256) void k_y(const u16* __restrict__ Xp, const u16* __restrict__ HT,
                                           const float* __restrict__ c, float* __restrict__ Y) {
  __shared__ __align__(16) u16 ldsA[2 * 128 * 32];
  __shared__ __align__(16) u16 ldsB[2 * 64 * 32];
  const int bid0 = blockIdx.x;
  const int bid = (bid0 & 7) * 128 + (bid0 >> 3);   // bijective: 1024 = 8 XCD * 128
  const int b  = bid >> 7;
  const int tm = (bid >> 2) & 31;
  const int tn = bid & 3;
  const u16* Ag = Xp + (size_t)(b * Nn + tm * 128) * Dd;
  const u16* Bg = HT + (size_t)(b * Dd + tn * 64) * Dd;
  f32x4 acc[4][2];
  acc_zero<2>(acc);
  gemm_tile<2>(Ag, Dd, Bg, Dd, 0, Dd / 32, ldsA, ldsB, acc);
  const int tid = threadIdx.x, wave = tid >> 6, lane = tid & 63;
  const int wr = wave >> 1, wc = wave & 1, lr = lane & 15, lq = lane >> 4;
  float* base = Y + (size_t)(b * Nn + tm * 128) * Dd + tn * 64;
#pragma unroll
  for (int n = 0; n < 2; ++n) {
    const int col = wc * 32 + n * 16 + lr;
    const float cv = c[b * Dd + tn * 64 + col];
#pragma unroll
    for (int m = 0; m < 4; ++m)
#pragma unroll
      for (int j = 0; j < 4; ++j)
        base[(size_t)(wr * 64 + m * 16 + lq * 4 + j) * Dd + col] = acc[m][n][j] + cv;
  }
}

// ---------------- launcher ----------------
extern "C" void kernel_launch(void* const* d_in, const int* in_sizes, int n_in,
                              void* d_out, int out_size, void* d_ws, size_t ws_size,
                              hipStream_t stream) {
  const float* X   = (const float*)d_in[0];
  const float* P   = (const float*)d_in[1];
  const float* Wh1 = (const float*)d_in[2];
  const float* bh1 = (const float*)d_in[3];
  const float* Wh2 = (const float*)d_in[4];
  const float* bh2 = (const float*)d_in[5];
  float* Y = (float*)d_out;
  char* ws = (char*)d_ws;

  // workspace layout (bytes)
  u16*   Xp     = (u16*)(ws);                     // 16,777,216
  u16*   XpT    = (u16*)(ws + 16777216);          // 16,777,216
  u16*   WhT1   = (u16*)(ws + 33554432);          //    262,144
  u16*   Wbf2   = (u16*)(ws + 33816576);          //    262,144
  u16*   G_part = (u16*)(ws + 34078720);          //  8,388,608  (8 bf16 split-K slabs)
  float* s_part = (float*)(ws + 42467328);        //    524,288
  float* s      = (float*)(ws + 42991616);        //      8,192
  float* c      = (float*)(ws + 42999808);        //      8,192
  u16*   Gb     = (u16*)(ws + 43008000);          //  1,048,576
  u16*   AT     = (u16*)(ws + 44056576);          //  2,097,152
  u16*   HT     = (u16*)(ws + 46153728);          //  1,048,576
  const size_t WS_NEED = 47202304;
  if (ws_size < WS_NEED) return;

  k_s1  <<<2144, 256, 0, stream>>>(X, P, Wh1, Wh2, Xp, XpT, s_part, WhT1, Wbf2);
  k_gram<<<512,  256, 0, stream>>>(XpT, G_part);
  k_gsum<<<264,  256, 0, stream>>>(G_part, s_part, Gb, s, c);
  k_pmAT<<<64,   256, 0, stream>>>(WhT1, Gb, bh1, s, bh2, AT, c);
  k_h   <<<32,   256, 0, stream>>>(Wbf2, AT, HT);
  k_y   <<<1024, 256, 0, stream>>>(Xp, HT, c, Y);
}

// Round 10
// 68.005 us; speedup vs baseline: 4.5397x; 1.0607x over previous
//
#include <hip/hip_runtime.h>

#define DEV static __device__ __forceinline__

typedef unsigned short u16;
typedef __bf16 bf16_t;
typedef __bf16 bf16x8 __attribute__((ext_vector_type(8)));
typedef float f32x4 __attribute__((ext_vector_type(4)));
typedef u16 u16x8 __attribute__((ext_vector_type(8)));

static constexpr int Bb = 8;     // batch
static constexpr int Nn = 4096;  // tokens per batch
static constexpr int Dd = 256;   // d
static constexpr int DP = 512;   // d_prime

// ---------------- async global->LDS (16B, wave-uniform LDS base + lane*16) ----------------
DEV void gload16(const void* g, void* l) {
  __builtin_amdgcn_global_load_lds(
      (__attribute__((address_space(1))) void*)(unsigned long long)(g),
      (__attribute__((address_space(3))) void*)(unsigned)(unsigned long long)(l),
      16, 0, 0);
}

DEV u16 f2bf(float x) { bf16_t h = (bf16_t)x; return __builtin_bit_cast(u16, h); }
DEV float bf2f(u16 v) { unsigned u = ((unsigned)v) << 16; return __builtin_bit_cast(float, u); }
DEV float gelu_exact(float x) { return 0.5f * x * (1.0f + erff(x * 0.70710678118654752f)); }

// ------- 128 x (NT*32) tile mainloop, TRIPLE-buffered, counted vmcnt (T3/T4-minimum) ------
// A: 128 rows x K ; B: NT*32 rows x K (B^T layout). 4 waves, 16x16x32 bf16 MFMA.
// ldsA: 3*128*32 u16 (24 KB). ldsB: 3*NT*32*32 u16 (NT=4: 24 KB, NT=2: 12 KB).
// Loop: issue loads(t+2) -> MFMA(t) -> vmcnt(NLD) [t+1 done, t+2 in flight] -> raw barrier.
// Raw s_barrier avoids the compiler's forced vmcnt(0) drain at __syncthreads (m97 stall).
// Ends with s_barrier: caller may alias the LDS region afterwards.
template <int NT>
DEV void gemm_tile(const u16* Ag, int lda, const u16* Bg, int ldb,
                   int k0, int ksteps, u16* ldsA, u16* ldsB, f32x4 acc[4][NT]) {
  constexpr int BCH  = NT / 2;         // B chunks (16 rows) per wave
  constexpr int ABUF = 4096;           // u16 per A buffer
  constexpr int BBUF = NT * 1024;      // u16 per B buffer
  const int tid  = threadIdx.x;
  const int wave = tid >> 6, lane = tid & 63;
  const int wr = wave >> 1, wc = wave & 1;
  const int lr = lane & 15, lk = (lane >> 4) * 8;
  const int srow = lane >> 2;          // 0..15 row within 16-row chunk
  const int skb  = (lane & 3) * 8;     // k element offset of this lane's 16B
  const int ca0 = wave * 2, ca1 = ca0 + 1;
  const size_t ga0 = (size_t)(ca0 * 16 + srow) * lda + skb;
  const size_t ga1 = (size_t)(ca1 * 16 + srow) * lda + skb;
  u16* la0 = ldsA + ca0 * 512; u16* la1 = ldsA + ca1 * 512;
  size_t gb[BCH]; u16* lb[BCH];
#pragma unroll
  for (int i = 0; i < BCH; ++i) {
    const int ch = wave * BCH + i;
    gb[i] = (size_t)(ch * 16 + srow) * ldb + skb;
    lb[i] = ldsB + ch * 512;
  }

  auto STAGE = [&](int kt, int buf) {
    const int kk = k0 + kt * 32;
    gload16(Ag + ga0 + kk, la0 + buf * ABUF);
    gload16(Ag + ga1 + kk, la1 + buf * ABUF);
#pragma unroll
    for (int i = 0; i < BCH; ++i) gload16(Bg + gb[i] + kk, lb[i] + buf * BBUF);
  };

  // prologue: stage steps 0 and 1; guarantee step 0 resident (ksteps >= 2 always)
  STAGE(0, 0);
  STAGE(1, 1);
  if constexpr (NT == 2) asm volatile("s_waitcnt vmcnt(3)" ::: "memory");
  else                   asm volatile("s_waitcnt vmcnt(4)" ::: "memory");
  __builtin_amdgcn_s_barrier();
  __builtin_amdgcn_sched_barrier(0);

  int cur = 0;
  for (int kt = 0; kt < ksteps; ++kt) {
    const int sb = (cur + 2 >= 3) ? cur - 1 : cur + 2;   // (cur+2)%3
    const bool do_stage = (kt + 2 < ksteps);
    if (do_stage) STAGE(kt + 2, sb);                     // issue BEFORE compute (overlap)
    const u16* pa = ldsA + cur * ABUF;
    const u16* pb = ldsB + cur * BBUF;
    bf16x8 af[4], bfr[NT];
#pragma unroll
    for (int m = 0; m < 4; ++m)
      af[m] = *(const bf16x8*)(pa + (wr * 64 + m * 16 + lr) * 32 + lk);
#pragma unroll
    for (int n = 0; n < NT; ++n)
      bfr[n] = *(const bf16x8*)(pb + (wc * (NT * 16) + n * 16 + lr) * 32 + lk);
#pragma unroll
    for (int m = 0; m < 4; ++m)
#pragma unroll
      for (int n = 0; n < NT; ++n)
        acc[m][n] = __builtin_amdgcn_mfma_f32_16x16x32_bf16(af[m], bfr[n], acc[m][n], 0, 0, 0);
    if (kt + 1 < ksteps) {
      if (do_stage) {         // allow the NLD loads of step t+2 to stay in flight
        if constexpr (NT == 2) asm volatile("s_waitcnt vmcnt(3)" ::: "memory");
        else                   asm volatile("s_waitcnt vmcnt(4)" ::: "memory");
      } else {                // tail: only t+1's loads outstanding
        asm volatile("s_waitcnt vmcnt(0)" ::: "memory");
      }
      __builtin_amdgcn_s_barrier();
      __builtin_amdgcn_sched_barrier(0);
    }
    cur = (cur + 1 == 3) ? 0 : cur + 1;
  }
  __builtin_amdgcn_s_barrier();   // callers may alias/reuse the LDS region after return
}

template <int NT>
DEV void acc_zero(f32x4 acc[4][NT]) {
#pragma unroll
  for (int m = 0; m < 4; ++m)
#pragma unroll
    for (int n = 0; n < NT; ++n) {
      f32x4 z = {0.f, 0.f, 0.f, 0.f};
      acc[m][n] = z;
    }
}

// ============ S1 mega-kernel: Xp/XpT/s_part (blocks 0..2047) + Wh prep (2048..2143) ========
__global__ __launch_bounds__(256) void k_s1(const float* __restrict__ X, const float* __restrict__ P,
                                            const float* __restrict__ Wh1, const float* __restrict__ Wh2,
                                            u16* __restrict__ Xp, u16* __restrict__ XpT,
                                            float* __restrict__ s_part,
                                            u16* __restrict__ WhT1, u16* __restrict__ Wbf2) {
  __shared__ u16 lt[64 * 65];
  const int bid = blockIdx.x;
  const int t = threadIdx.x;
  if (bid < 2048) {
    const int b  = bid >> 8;
    const int nt = (bid >> 2) & 63;
    const int dt = bid & 3;
    const int n0 = nt * 64, d0 = dt * 64;
    const int r = t >> 2, c0 = (t & 3) * 16;
    const size_t gbase = ((size_t)(b * Nn + n0 + r)) * Dd + d0 + c0;
    u16x8 lo, hi;
#pragma unroll
    for (int i = 0; i < 4; ++i) {
      float4 xv = *(const float4*)(X + gbase + i * 4);
      float4 pv = *(const float4*)(P + gbase + i * 4);
      u16 a0 = f2bf(xv.x + pv.x), a1 = f2bf(xv.y + pv.y);
      u16 a2 = f2bf(xv.z + pv.z), a3 = f2bf(xv.w + pv.w);
      if (i < 2) { lo[i*4+0]=a0; lo[i*4+1]=a1; lo[i*4+2]=a2; lo[i*4+3]=a3; }
      else       { int q=(i-2)*4; hi[q+0]=a0; hi[q+1]=a1; hi[q+2]=a2; hi[q+3]=a3; }
      lt[r * 65 + c0 + i*4 + 0] = a0; lt[r * 65 + c0 + i*4 + 1] = a1;
      lt[r * 65 + c0 + i*4 + 2] = a2; lt[r * 65 + c0 + i*4 + 3] = a3;
    }
    *(u16x8*)(Xp + gbase)     = lo;
    *(u16x8*)(Xp + gbase + 8) = hi;
    __syncthreads();
    const int dd = t >> 2, nc0 = (t & 3) * 16;
    u16x8 olo, ohi;
    float colsum = 0.f;
#pragma unroll
    for (int i = 0; i < 8; ++i) { olo[i] = lt[(nc0 + i) * 65 + dd]; colsum += bf2f(olo[i]); }
#pragma unroll
    for (int i = 0; i < 8; ++i) { ohi[i] = lt[(nc0 + 8 + i) * 65 + dd]; colsum += bf2f(ohi[i]); }
    const size_t obase = ((size_t)(b * Dd + d0 + dd)) * Nn + n0 + nc0;
    *(u16x8*)(XpT + obase)     = olo;
    *(u16x8*)(XpT + obase + 8) = ohi;
    colsum += __shfl_xor(colsum, 1);
    colsum += __shfl_xor(colsum, 2);
    if ((t & 3) == 0) s_part[(size_t)(b * 64 + nt) * Dd + d0 + dd] = colsum;
  } else if (bid < 2048 + 32) {
    const int wb = bid - 2048;
    const int rt = (wb >> 3) & 3;
    const int ct = wb & 7;
    const int r0 = rt * 64, c0t = ct * 64;
    const int r = t >> 2, c0 = (t & 3) * 16;
    const size_t gbase = (size_t)(r0 + r) * DP + c0t + c0;
#pragma unroll
    for (int i = 0; i < 4; ++i) {
      float4 v = *(const float4*)(Wh1 + gbase + i * 4);
      lt[r * 65 + c0 + i*4 + 0] = f2bf(v.x); lt[r * 65 + c0 + i*4 + 1] = f2bf(v.y);
      lt[r * 65 + c0 + i*4 + 2] = f2bf(v.z); lt[r * 65 + c0 + i*4 + 3] = f2bf(v.w);
    }
    __syncthreads();
    const int pp = t >> 2, dc0 = (t & 3) * 16;
    u16x8 olo, ohi;
#pragma unroll
    for (int i = 0; i < 8; ++i) olo[i] = lt[(dc0 + i) * 65 + pp];
#pragma unroll
    for (int i = 0; i < 8; ++i) ohi[i] = lt[(dc0 + 8 + i) * 65 + pp];
    u16* out = WhT1 + (size_t)(c0t + pp) * Dd + r0 + dc0;
    *(u16x8*)(out)     = olo;
    *(u16x8*)(out + 8) = ohi;
  } else {
    const int idx = ((bid - 2048 - 32) * 256 + t) * 8;
    float4 v0 = *(const float4*)(Wh2 + idx);
    float4 v1 = *(const float4*)(Wh2 + idx + 4);
    u16x8 o;
    o[0]=f2bf(v0.x); o[1]=f2bf(v0.y); o[2]=f2bf(v0.z); o[3]=f2bf(v0.w);
    o[4]=f2bf(v1.x); o[5]=f2bf(v1.y); o[6]=f2bf(v1.z); o[7]=f2bf(v1.w);
    *(u16x8*)(Wbf2 + idx) = o;
  }
}

// ====== k_gram: G_part[kc][b][256][256] (bf16) = XpT[b] @ XpT[b]^T K-slice, plain stores ===
// 512 blocks of 128x64 tiles (NT=2): 8b * 2tm * 4tn * 8kc. XCD-swizzled: batch b -> XCD b.
__global__ __launch_bounds__(256) void k_gram(const u16* __restrict__ XpT, u16* __restrict__ G_part) {
  __shared__ __align__(16) u16 ldsA[3 * 128 * 32];
  __shared__ __align__(16) u16 ldsB[3 * 64 * 32];
  const int bid0 = blockIdx.x;
  const int bid = (bid0 & 7) * 64 + (bid0 >> 3);   // bijective: 512 = 8 XCD * 64
  const int kc = bid & 7;
  const int tn = (bid >> 3) & 3;
  const int tm = (bid >> 5) & 1;
  const int b  = bid >> 6;
  const u16* Ag = XpT + (size_t)(b * Dd + tm * 128) * Nn;
  const u16* Bg = XpT + (size_t)(b * Dd + tn * 64) * Nn;
  f32x4 acc[4][2];
  acc_zero<2>(acc);
  gemm_tile<2>(Ag, Nn, Bg, Nn, kc * 512, 16, ldsA, ldsB, acc);
  const int tid = threadIdx.x, wave = tid >> 6, lane = tid & 63;
  const int wr = wave >> 1, wc = wave & 1, lr = lane & 15, lq = lane >> 4;
  u16* base = G_part + (size_t)kc * (Bb * Dd * Dd) + (size_t)(b * Dd + tm * 128) * Dd + tn * 64;
#pragma unroll
  for (int m = 0; m < 4; ++m)
#pragma unroll
    for (int n = 0; n < 2; ++n)
#pragma unroll
      for (int j = 0; j < 4; ++j)
        base[(size_t)(wr * 64 + m * 16 + lq * 4 + j) * Dd + wc * 32 + n * 16 + lr] =
            f2bf(acc[m][n][j]);
}

// ==== k_gsum: blocks 0..7 -> s reduce + zero c ; blocks 8..263 -> Gb = bf16(sum slabs) ====
__global__ __launch_bounds__(256) void k_gsum(const u16* __restrict__ G_part,
                                              const float* __restrict__ s_part,
                                              u16* __restrict__ Gb, float* __restrict__ s,
                                              float* __restrict__ c) {
  const int bid = blockIdx.x;
  const int t = threadIdx.x;
  if (bid < 8) {
    const int b = bid, d = t;
    float sum = 0.f;
#pragma unroll 8
    for (int nt = 0; nt < 64; ++nt) sum += s_part[(size_t)(b * 64 + nt) * Dd + d];
    s[b * Dd + d] = sum;
    c[b * Dd + d] = 0.f;
  } else {
    const int e = ((bid - 8) * 256 + t) * 8;
    float a[8] = {0.f,0.f,0.f,0.f,0.f,0.f,0.f,0.f};
#pragma unroll
    for (int k = 0; k < 8; ++k) {
      u16x8 v = *(const u16x8*)(G_part + (size_t)k * (Bb * Dd * Dd) + e);
#pragma unroll
      for (int i = 0; i < 8; ++i) a[i] += bf2f(v[i]);
    }
    u16x8 o;
#pragma unroll
    for (int i = 0; i < 8; ++i) o[i] = f2bf(a[i]);
    *(u16x8*)(Gb + e) = o;
  }
}

// ==== k_pmAT: AT[b][d][p] = bf16(gelu(Wh1^T G + bh1 ⊗ s)); c[b][d] += bh2·A partial ======
// LDS: 48 KB shared block; ct (34.8 KB) aliases the gemm buffers (safe: gemm ends w/ barrier)
__global__ __launch_bounds__(256) void k_pmAT(const u16* __restrict__ WhT1, const u16* __restrict__ Gb,
                                              const float* __restrict__ bh1, const float* __restrict__ s,
                                              const float* __restrict__ bh2,
                                              u16* __restrict__ AT, float* __restrict__ c) {
  __shared__ __align__(16) u16 smem[24576];      // 48 KB
  u16* ldsA = smem;                               // 3*4096 u16
  u16* ldsB = smem + 12288;                       // 3*4096 u16
  u16* ct   = smem;                               // 128*136 u16, aliases (post-gemm only)
  const int bid = blockIdx.x;        // 8b * 4tm(p) * 2tn(d)
  const int tn = bid & 1;
  const int tm = (bid >> 1) & 3;
  const int b  = bid >> 3;
  const int p0 = tm * 128, d0 = tn * 128;
  const u16* Ag = WhT1 + (size_t)p0 * Dd;
  const u16* Bg = Gb + (size_t)(b * Dd + d0) * Dd;
  f32x4 acc[4][4];
  acc_zero<4>(acc);
  gemm_tile<4>(Ag, Dd, Bg, Dd, 0, Dd / 32, ldsA, ldsB, acc);
  const int tid = threadIdx.x, wave = tid >> 6, lane = tid & 63;
  const int wr = wave >> 1, wc = wave & 1, lr = lane & 15, lq = lane >> 4;
#pragma unroll
  for (int n = 0; n < 4; ++n) {
    const int col = wc * 64 + n * 16 + lr;
    const float sv = s[b * Dd + d0 + col];
#pragma unroll
    for (int m = 0; m < 4; ++m) {
#pragma unroll
      for (int j = 0; j < 4; ++j) {
        const int row = wr * 64 + m * 16 + lq * 4 + j;
        const float pm = acc[m][n][j] + bh1[p0 + row] * sv;
        ct[col * 136 + row] = f2bf(gelu_exact(pm));
      }
    }
  }
  __syncthreads();
#pragma unroll
  for (int it = 0; it < 8; ++it) {
    const int id = tid + it * 256;
    const int dl = id >> 4, ch = id & 15;
    *(u16x8*)(AT + (size_t)(b * Dd + d0 + dl) * DP + p0 + ch * 8) =
        *(const u16x8*)(ct + dl * 136 + ch * 8);
  }
  const int ccol = tid >> 1;
  const int chalf = tid & 1;
  float csum = 0.f;
#pragma unroll
  for (int q = 0; q < 8; ++q) {
    u16x8 av = *(const u16x8*)(ct + ccol * 136 + chalf * 64 + q * 8);
#pragma unroll
    for (int i = 0; i < 8; ++i) csum += bh2[p0 + chalf * 64 + q * 8 + i] * bf2f(av[i]);
  }
  csum += __shfl_xor(csum, 1);
  if (chalf == 0) atomicAdd(c + b * Dd + d0 + ccol, csum);
}

// ---------------- kernel: HT[b][d_out][kd] = bf16(Wh2 @ A)^T (aliased LDS) ----------------
__global__ __launch_bounds__(256) void k_h(const u16* __restrict__ Wbf2, const u16* __restrict__ AT,
                                           u16* __restrict__ HT) {
  __shared__ __align__(16) u16 smem[24576];      // 48 KB
  u16* ldsA = smem;
  u16* ldsB = smem + 12288;
  u16* ct   = smem;
  const int bid = blockIdx.x;
  const int tn = bid & 1;
  const int tm = (bid >> 1) & 1;
  const int b  = bid >> 2;
  const int k0 = tm * 128, d0 = tn * 128;
  const u16* Ag = Wbf2 + (size_t)k0 * DP;
  const u16* Bg = AT + (size_t)(b * Dd + d0) * DP;
  f32x4 acc[4][4];
  acc_zero<4>(acc);
  gemm_tile<4>(Ag, DP, Bg, DP, 0, DP / 32, ldsA, ldsB, acc);
  const int tid = threadIdx.x, wave = tid >> 6, lane = tid & 63;
  const int wr = wave >> 1, wc = wave & 1, lr = lane & 15, lq = lane >> 4;
#pragma unroll
  for (int n = 0; n < 4; ++n) {
    const int col = wc * 64 + n * 16 + lr;
#pragma unroll
    for (int m = 0; m < 4; ++m)
#pragma unroll
      for (int j = 0; j < 4; ++j)
        ct[col * 136 + wr * 64 + m * 16 + lq * 4 + j] = f2bf(acc[m][n][j]);
  }
  __syncthreads();
#pragma unroll
  for (int it = 0; it < 8; ++it) {
    const int id = tid + it * 256;
    const int dl = id >> 4, ch = id & 15;
    *(u16x8*)(HT + (size_t)(b * Dd + d0 + dl) * Dd + k0 + ch * 8) =
        *(const u16x8*)(ct + dl * 136 + ch * 8);
  }
}

// -------- kernel: Y[b][n][d] = Xp[b] @ H[b] + c[b][d]  (1024 blocks of 128x64, NT=2) ------
__global__ __launch_bounds__(256) void k_y(const u16* __restrict__ Xp, const u16* __restrict__ HT,
                                           const float* __restrict__ c, float* __restrict__ Y) {
  __shared__ __align__(16) u16 ldsA[3 * 128 * 32];
  __shared__ __align__(16) u16 ldsB[3 * 64 * 32];
  const int bid0 = blockIdx.x;
  const int bid = (bid0 & 7) * 128 + (bid0 >> 3);   // bijective: 1024 = 8 XCD * 128
  const int b  = bid >> 7;
  const int tm = (bid >> 2) & 31;
  const int tn = bid & 3;
  const u16* Ag = Xp + (size_t)(b * Nn + tm * 128) * Dd;
  const u16* Bg = HT + (size_t)(b * Dd + tn * 64) * Dd;
  f32x4 acc[4][2];
  acc_zero<2>(acc);
  gemm_tile<2>(Ag, Dd, Bg, Dd, 0, Dd / 32, ldsA, ldsB, acc);
  const int tid = threadIdx.x, wave = tid >> 6, lane = tid & 63;
  const int wr = wave >> 1, wc = wave & 1, lr = lane & 15, lq = lane >> 4;
  float* base = Y + (size_t)(b * Nn + tm * 128) * Dd + tn * 64;
#pragma unroll
  for (int n = 0; n < 2; ++n) {
    const int col = wc * 32 + n * 16 + lr;
    const float cv = c[b * Dd + tn * 64 + col];
#pragma unroll
    for (int m = 0; m < 4; ++m)
#pragma unroll
      for (int j = 0; j < 4; ++j)
        base[(size_t)(wr * 64 + m * 16 + lq * 4 + j) * Dd + col] = acc[m][n][j] + cv;
  }
}

// ---------------- launcher ----------------
extern "C" void kernel_launch(void* const* d_in, const int* in_sizes, int n_in,
                              void* d_out, int out_size, void* d_ws, size_t ws_size,
                              hipStream_t stream) {
  const float* X   = (const float*)d_in[0];
  const float* P   = (const float*)d_in[1];
  const float* Wh1 = (const float*)d_in[2];
  const float* bh1 = (const float*)d_in[3];
  const float* Wh2 = (const float*)d_in[4];
  const float* bh2 = (const float*)d_in[5];
  float* Y = (float*)d_out;
  char* ws = (char*)d_ws;

  // workspace layout (bytes)
  u16*   Xp     = (u16*)(ws);                     // 16,777,216
  u16*   XpT    = (u16*)(ws + 16777216);          // 16,777,216
  u16*   WhT1   = (u16*)(ws + 33554432);          //    262,144
  u16*   Wbf2   = (u16*)(ws + 33816576);          //    262,144
  u16*   G_part = (u16*)(ws + 34078720);          //  8,388,608  (8 bf16 split-K slabs)
  float* s_part = (float*)(ws + 42467328);        //    524,288
  float* s      = (float*)(ws + 42991616);        //      8,192
  float* c      = (float*)(ws + 42999808);        //      8,192
  u16*   Gb     = (u16*)(ws + 43008000);          //  1,048,576
  u16*   AT     = (u16*)(ws + 44056576);          //  2,097,152
  u16*   HT     = (u16*)(ws + 46153728);          //  1,048,576
  const size_t WS_NEED = 47202304;
  if (ws_size < WS_NEED) return;

  k_s1  <<<2144, 256, 0, stream>>>(X, P, Wh1, Wh2, Xp, XpT, s_part, WhT1, Wbf2);
  k_gram<<<512,  256, 0, stream>>>(XpT, G_part);
  k_gsum<<<264,  256, 0, stream>>>(G_part, s_part, Gb, s, c);
  k_pmAT<<<64,   256, 0, stream>>>(WhT1, Gb, bh1, s, bh2, AT, c);
  k_h   <<<32,   256, 0, stream>>>(Wbf2, AT, HT);
  k_y   <<<1024, 256, 0, stream>>>(Xp, HT, c, Y);
}